// Round 3
// baseline (187.858 us; speedup 1.0000x reference)
//
#include <hip/hip_runtime.h>
#include <hip/hip_bf16.h>

typedef __attribute__((ext_vector_type(8))) short bf16x8;
typedef __attribute__((ext_vector_type(4))) float f32x4;

#define DEVI __device__ __forceinline__

DEVI unsigned short f2bf(float f) {
  __hip_bfloat16 h = __float2bfloat16(f);
  return *reinterpret_cast<unsigned short*>(&h);
}

DEVI void gload16(const void* g, void* l) {
  __builtin_amdgcn_global_load_lds((const __attribute__((address_space(1))) void*)g,
                                   (__attribute__((address_space(3))) void*)l, 16, 0, 0);
}

// ---------------- weight fp32 -> bf16 ----------------
__global__ __launch_bounds__(256) void k_f2bf(const float* __restrict__ in,
                                              unsigned short* __restrict__ out, int n) {
  int i = blockIdx.x * 256 + threadIdx.x;
  if (i < n) out[i] = f2bf(in[i]);
}

// ---------------- LN1 + transpose: x[b][c][p] -> xt fp32 [tok][c], xln bf16 [tok][c] ----------------
__global__ __launch_bounds__(256) void k_ln1(const float* __restrict__ x,
                                             const float* __restrict__ g,
                                             const float* __restrict__ be,
                                             float* __restrict__ xt,
                                             unsigned short* __restrict__ xln) {
  __shared__ float tile[256][33];
  const int b  = blockIdx.y;
  const int p0 = blockIdx.x * 32;
  const int t  = threadIdx.x;
  const float* src = x + ((size_t)b * 256 + t) * 1024 + p0;
#pragma unroll
  for (int j = 0; j < 32; j += 4) {
    float4 v = *(const float4*)(src + j);
    tile[t][j] = v.x; tile[t][j + 1] = v.y; tile[t][j + 2] = v.z; tile[t][j + 3] = v.w;
  }
  __syncthreads();
  const int w = t >> 6, l = t & 63;
#pragma unroll
  for (int i = 0; i < 8; i++) {
    const int p = w * 8 + i;
    float s = 0.f, ss = 0.f;
#pragma unroll
    for (int q = 0; q < 4; q++) {
      float v = tile[l + 64 * q][p];
      s += v; ss += v * v;
    }
#pragma unroll
    for (int msk = 1; msk < 64; msk <<= 1) {
      s  += __shfl_xor(s, msk);
      ss += __shfl_xor(ss, msk);
    }
    const float mean = s * (1.f / 256.f);
    const float var  = ss * (1.f / 256.f) - mean * mean;
    const float rs   = rsqrtf(var + 1e-5f);
    const size_t token = (size_t)b * 1024 + p0 + p;
#pragma unroll
    for (int q = 0; q < 4; q++) {
      const int c = l + 64 * q;
      const float v = tile[c][p];
      xt[token * 256 + c]  = v;
      xln[token * 256 + c] = f2bf((v - mean) * rs * g[c] + be[c]);
    }
  }
}

// ---------------- GEMM: C[M,N] = A[M,K] @ B[N,K]^T, bf16 in, fp32 acc ----------------
// 1D grid, XCD-swizzled so one A-panel's n-tiles stream on one XCD L2.
template <int EPI, int NN>
__global__ __launch_bounds__(256) void k_gemm(const unsigned short* __restrict__ A, int lda,
                                              const unsigned short* __restrict__ Bw, int ldb,
                                              int K,
                                              const float* __restrict__ bias,
                                              const float* __restrict__ addend, int ldadd,
                                              float* __restrict__ outf,
                                              unsigned short* __restrict__ outb, int ldc) {
  __shared__ __align__(16) unsigned short As[128 * 64];
  __shared__ __align__(16) unsigned short Bs[128 * 64];
  const int nwg = gridDim.x;
  const int id  = (blockIdx.x & 7) * (nwg >> 3) + (blockIdx.x >> 3);
  const int m0  = (id / NN) * 128, n0 = (id % NN) * 128;
  const int t  = threadIdx.x;
  const int w  = t >> 6, l = t & 63;
  const int wm = (w >> 1) * 64, wn = (w & 1) * 64;
  const int lr = l & 15, lk = (l >> 4) * 8;
  f32x4 acc[4][4] = {};
  const int nkt = K >> 6;
  for (int kt = 0; kt < nkt; ++kt) {
    __syncthreads();
#pragma unroll
    for (int i = 0; i < 4; i++) {
      const int e = i * 2048 + t * 8;
      const int r = e >> 6, c = e & 63;
      gload16(&A[(size_t)(m0 + r) * lda + kt * 64 + c], &As[e]);
      gload16(&Bw[(size_t)(n0 + r) * ldb + kt * 64 + c], &Bs[e]);
    }
    __syncthreads();
#pragma unroll
    for (int ks = 0; ks < 2; ks++) {
      bf16x8 af[4], bfr[4];
#pragma unroll
      for (int i = 0; i < 4; i++) af[i] = *(const bf16x8*)&As[(wm + i * 16 + lr) * 64 + ks * 32 + lk];
#pragma unroll
      for (int j = 0; j < 4; j++) bfr[j] = *(const bf16x8*)&Bs[(wn + j * 16 + lr) * 64 + ks * 32 + lk];
#pragma unroll
      for (int i = 0; i < 4; i++)
#pragma unroll
        for (int j = 0; j < 4; j++)
          acc[i][j] = __builtin_amdgcn_mfma_f32_16x16x32_bf16(af[i], bfr[j], acc[i][j], 0, 0, 0);
    }
  }
#pragma unroll
  for (int i = 0; i < 4; i++)
#pragma unroll
    for (int j = 0; j < 4; j++)
#pragma unroll
      for (int r = 0; r < 4; r++) {
        const int gr = m0 + wm + i * 16 + (l >> 4) * 4 + r;
        const int gc = n0 + wn + j * 16 + (l & 15);
        const float v = acc[i][j][r];
        if constexpr (EPI == 0) {
          outb[(size_t)gr * ldc + gc] = f2bf(v);
        } else if constexpr (EPI == 1) {
          outf[(size_t)gr * ldc + gc] = v + bias[gc] + addend[(size_t)gr * ldadd + gc];
        } else if constexpr (EPI == 2) {
          const float z = v + bias[gc];
          outb[(size_t)gr * ldc + gc] = f2bf(z > 0.f ? z : 0.f);
        } else {
          outf[(size_t)gr * ldc + gc] = v + bias[gc] + addend[(size_t)gr * ldadd + gc];
        }
      }
}

// ---------------- flash attention (swapped QK^T + defer-max, exp2 domain) ----------------
// qkv bf16 [tok][768]: q at [h*32], k at [256+h*32], v at [512+h*32]
// 512 blocks (XCD-swizzled) x 512 threads: 4 q-tiles of 256 rows x 128 bh.
// 8 waves; wave = 32 q rows (2 x 16).
__global__ __launch_bounds__(512) void k_attn(const unsigned short* __restrict__ qkv,
                                              unsigned short* __restrict__ attn_out) {
  __shared__ __align__(16) unsigned short Ks[64][40];
  __shared__ __align__(16) unsigned short Vt[32][72];
  __shared__ __align__(16) unsigned short Pq[8][32][72];

  const int bid  = blockIdx.x;
  const int wgid = (bid & 7) * 64 + (bid >> 3);  // bijective (512 % 8 == 0)
  const int bh = wgid >> 2;
  const int qt = wgid & 3;
  const int b = bh >> 3, h = bh & 7;
  const int q0 = qt * 256;
  const int t = threadIdx.x, w = t >> 6, l = t & 63;
  const int lr = l & 15, hi = l >> 4, lk = hi * 8;
  const size_t base = (size_t)b * 1024 * 768;
  const float c2 = 1.4426950408889634f * 0.17677669529663687f;  // log2e / sqrt(32)

  // Q fragments: wave handles 32 q rows (2 x 16)
  bf16x8 qf[2];
#pragma unroll
  for (int qi = 0; qi < 2; qi++)
    qf[qi] = *(const bf16x8*)&qkv[base + (size_t)(q0 + w * 32 + qi * 16 + lr) * 768 + h * 32 + lk];

  f32x4 o[2][2] = {};
  float m2[2]   = {0.f, 0.f};     // deferred running max (log2 domain)
  float lsum[2] = {0.f, 0.f};
  const f32x4 z4 = {0.f, 0.f, 0.f, 0.f};

  const int stok = t >> 3;        // 0..63 : staged token
  const int sd0  = (t & 7) * 4;   // 0..28 : staged d-offset (4 elems)
  const int vrot = sd0 >> 2;      // rotation to break Vt write bank degeneracy

  for (int kc = 0; kc < 16; kc++) {
    const size_t rbase = base + (size_t)(kc * 64 + stok) * 768 + h * 32 + sd0;
    const ushort4 kv_k = *(const ushort4*)&qkv[rbase + 256];
    const ushort4 kv_v = *(const ushort4*)&qkv[rbase + 512];
    __syncthreads();
    *(ushort4*)&Ks[stok][sd0] = kv_k;
    const unsigned short* vv = (const unsigned short*)&kv_v;
#pragma unroll
    for (int j = 0; j < 4; j++) {
      const int jj = (j + vrot) & 3;
      Vt[sd0 + jj][stok] = vv[jj];
    }
    __syncthreads();

    bf16x8 kf[4];
#pragma unroll
    for (int blk = 0; blk < 4; blk++) kf[blk] = *(const bf16x8*)&Ks[blk * 16 + lr][lk];

#pragma unroll
    for (int qi = 0; qi < 2; qi++) {
      // St = K @ Q^T : lane holds score(q = lr, key = blk*16 + hi*4 + r)
      f32x4 s[4];
#pragma unroll
      for (int blk = 0; blk < 4; blk++)
        s[blk] = __builtin_amdgcn_mfma_f32_16x16x32_bf16(kf[blk], qf[qi], z4, 0, 0, 0);

      float pm = s[0][0];
#pragma unroll
      for (int blk = 0; blk < 4; blk++)
#pragma unroll
        for (int r = 0; r < 4; r++) pm = fmaxf(pm, s[blk][r]);

      if (!__all(pm * c2 <= m2[qi] + 11.54f)) {  // defer-max slow path
        float mx = pm;
        mx = fmaxf(mx, __shfl_xor(mx, 16));
        mx = fmaxf(mx, __shfl_xor(mx, 32));
        const float m2n = fmaxf(m2[qi], mx * c2);
        const float d2  = m2[qi] - m2n;
        lsum[qi] *= exp2f(d2);
#pragma unroll
        for (int r = 0; r < 4; r++) {
          const float a = exp2f(__shfl(d2, hi * 4 + r));
          o[qi][0][r] *= a; o[qi][1][r] *= a;
        }
        m2[qi] = m2n;
      }

      float ls = 0.f;
#pragma unroll
      for (int blk = 0; blk < 4; blk++) {
        const float p0 = exp2f(fmaf(s[blk][0], c2, -m2[qi]));
        const float p1 = exp2f(fmaf(s[blk][1], c2, -m2[qi]));
        const float p2 = exp2f(fmaf(s[blk][2], c2, -m2[qi]));
        const float p3 = exp2f(fmaf(s[blk][3], c2, -m2[qi]));
        ls += (p0 + p1) + (p2 + p3);
        ushort4 us;
        us.x = f2bf(p0); us.y = f2bf(p1); us.z = f2bf(p2); us.w = f2bf(p3);
        *(ushort4*)&Pq[w][qi * 16 + lr][blk * 16 + hi * 4] = us;
      }
      lsum[qi] += ls;
    }

    // O += P @ V
#pragma unroll
    for (int ks = 0; ks < 2; ks++) {
      const bf16x8 v0f = *(const bf16x8*)&Vt[lr][ks * 32 + lk];
      const bf16x8 v1f = *(const bf16x8*)&Vt[16 + lr][ks * 32 + lk];
#pragma unroll
      for (int qi = 0; qi < 2; qi++) {
        const bf16x8 pa = *(const bf16x8*)&Pq[w][qi * 16 + lr][ks * 32 + lk];
        o[qi][0] = __builtin_amdgcn_mfma_f32_16x16x32_bf16(pa, v0f, o[qi][0], 0, 0, 0);
        o[qi][1] = __builtin_amdgcn_mfma_f32_16x16x32_bf16(pa, v1f, o[qi][1], 0, 0, 0);
      }
    }
  }

#pragma unroll
  for (int qi = 0; qi < 2; qi++) {
    float lsq = lsum[qi];
    lsq += __shfl_xor(lsq, 16);
    lsq += __shfl_xor(lsq, 32);
#pragma unroll
    for (int r = 0; r < 4; r++) {
      const int qloc = hi * 4 + r;
      const float inv = 1.f / __shfl(lsq, qloc);
      const int row = q0 + w * 32 + qi * 16 + qloc;
      attn_out[(size_t)(b * 1024 + row) * 256 + h * 32 + lr]      = f2bf(o[qi][0][r] * inv);
      attn_out[(size_t)(b * 1024 + row) * 256 + h * 32 + 16 + lr] = f2bf(o[qi][1][r] * inv);
    }
  }
}

// ---------------- LN2: y fp32 [tok][256] -> yln bf16 ----------------
__global__ __launch_bounds__(256) void k_ln2(const float* __restrict__ y,
                                             const float* __restrict__ g,
                                             const float* __restrict__ be,
                                             unsigned short* __restrict__ yln) {
  const int row = blockIdx.x * 4 + (threadIdx.x >> 6);
  const int l = threadIdx.x & 63;
  const float* yr = y + (size_t)row * 256;
  const float4 v = *(const float4*)(yr + l * 4);
  float s  = v.x + v.y + v.z + v.w;
  float ss = v.x * v.x + v.y * v.y + v.z * v.z + v.w * v.w;
#pragma unroll
  for (int msk = 1; msk < 64; msk <<= 1) {
    s  += __shfl_xor(s, msk);
    ss += __shfl_xor(ss, msk);
  }
  const float mean = s * (1.f / 256.f);
  const float var  = ss * (1.f / 256.f) - mean * mean;
  const float rs   = rsqrtf(var + 1e-5f);
  const float4 gv  = *(const float4*)(g + l * 4);
  const float4 bv  = *(const float4*)(be + l * 4);
  ushort4 o;
  o.x = f2bf((v.x - mean) * rs * gv.x + bv.x);
  o.y = f2bf((v.y - mean) * rs * gv.y + bv.y);
  o.z = f2bf((v.z - mean) * rs * gv.z + bv.z);
  o.w = f2bf((v.w - mean) * rs * gv.w + bv.w);
  *(ushort4*)&yln[(size_t)row * 256 + l * 4] = o;
}

// ---------------- output transpose: z[b][s][c] -> out[b][c][s] ----------------
__global__ __launch_bounds__(256) void k_tout(const float* __restrict__ z,
                                              float* __restrict__ out) {
  __shared__ float tile[32][33];
  const int b  = blockIdx.z;
  const int c0 = blockIdx.y * 32, p0 = blockIdx.x * 32;
  const int tx = threadIdx.x & 31, ty = threadIdx.x >> 5;
#pragma unroll
  for (int i = 0; i < 32; i += 8)
    tile[ty + i][tx] = z[((size_t)b * 1024 + p0 + ty + i) * 256 + c0 + tx];
  __syncthreads();
#pragma unroll
  for (int i = 0; i < 32; i += 8)
    out[((size_t)b * 256 + c0 + ty + i) * 1024 + p0 + tx] = tile[tx][ty + i];
}

// ---------------- launch ----------------
extern "C" void kernel_launch(void* const* d_in, const int* in_sizes, int n_in,
                              void* d_out, int out_size, void* d_ws, size_t ws_size,
                              hipStream_t stream) {
  const float* x      = (const float*)d_in[0];
  const float* w_qkv  = (const float*)d_in[1];
  const float* w_proj = (const float*)d_in[2];
  const float* b_proj = (const float*)d_in[3];
  const float* g1     = (const float*)d_in[4];
  const float* beta1  = (const float*)d_in[5];
  const float* g2     = (const float*)d_in[6];
  const float* beta2  = (const float*)d_in[7];
  const float* w1     = (const float*)d_in[8];
  const float* b1     = (const float*)d_in[9];
  const float* w2     = (const float*)d_in[10];
  const float* b2     = (const float*)d_in[11];
  float* out = (float*)d_out;
  char* ws = (char*)d_ws;

  constexpr size_t OFF_XT  = 0;                       // 16 MB fp32 [tok][256]
  constexpr size_t OFF_XLN = 16777216;                //  8 MB bf16
  constexpr size_t OFF_QKV = OFF_XLN + 8388608;       // 24 MB bf16 [tok][768]
  constexpr size_t OFF_ATT = OFF_QKV + 25165824;      //  8 MB bf16
  constexpr size_t OFF_Y   = OFF_ATT + 8388608;       // 16 MB fp32
  constexpr size_t OFF_YLN = OFF_Y + 16777216;        //  8 MB bf16
  constexpr size_t OFF_W   = OFF_YLN + 8388608;       // weights bf16
  constexpr size_t OFF_H1  = OFF_XLN;                 // alias: 32 MB bf16 [tok][1024]
  constexpr size_t OFF_Z   = OFF_XT;                  // alias: 16 MB fp32

  float*          xt    = (float*)(ws + OFF_XT);
  unsigned short* xln   = (unsigned short*)(ws + OFF_XLN);
  unsigned short* qkv   = (unsigned short*)(ws + OFF_QKV);
  unsigned short* attn  = (unsigned short*)(ws + OFF_ATT);
  float*          y     = (float*)(ws + OFF_Y);
  unsigned short* yln   = (unsigned short*)(ws + OFF_YLN);
  unsigned short* h1    = (unsigned short*)(ws + OFF_H1);
  float*          z     = (float*)(ws + OFF_Z);
  unsigned short* wqkvb = (unsigned short*)(ws + OFF_W);
  unsigned short* wprjb = (unsigned short*)(ws + OFF_W + 393216);
  unsigned short* w1b   = (unsigned short*)(ws + OFF_W + 393216 + 131072);
  unsigned short* w2b   = (unsigned short*)(ws + OFF_W + 393216 + 131072 + 524288);

  k_f2bf<<<768, 256, 0, stream>>>(w_qkv, wqkvb, 768 * 256);
  k_f2bf<<<256, 256, 0, stream>>>(w_proj, wprjb, 256 * 256);
  k_f2bf<<<1024, 256, 0, stream>>>(w1, w1b, 1024 * 256);
  k_f2bf<<<1024, 256, 0, stream>>>(w2, w2b, 256 * 1024);

  k_ln1<<<dim3(32, 16), 256, 0, stream>>>(x, g1, beta1, xt, xln);

  // qkv = xln @ w_qkv^T  [16384, 768]
  k_gemm<0, 6><<<768, 256, 0, stream>>>(xln, 256, wqkvb, 256, 256,
                                        nullptr, nullptr, 0, nullptr, qkv, 768);

  k_attn<<<512, 512, 0, stream>>>(qkv, attn);

  // y = attn @ w_proj^T + b_proj + xt
  k_gemm<1, 2><<<256, 256, 0, stream>>>(attn, 256, wprjb, 256, 256,
                                        b_proj, xt, 256, y, nullptr, 256);

  k_ln2<<<4096, 256, 0, stream>>>(y, g2, beta2, yln);

  // h1 = relu(yln @ w1^T + b1)
  k_gemm<2, 8><<<1024, 256, 0, stream>>>(yln, 256, w1b, 256, 256,
                                         b1, nullptr, 0, nullptr, h1, 1024);

  // z = h1 @ w2^T + b2 + y
  k_gemm<3, 2><<<256, 256, 0, stream>>>(h1, 1024, w2b, 1024, 1024,
                                        b2, y, 256, z, nullptr, 256);

  k_tout<<<dim3(32, 8, 16), 256, 0, stream>>>(z, out);
}

// Round 4
// 165.970 us; speedup vs baseline: 1.1319x; 1.1319x over previous
//
#include <hip/hip_runtime.h>
#include <hip/hip_bf16.h>

typedef __attribute__((ext_vector_type(8))) short bf16x8;
typedef __attribute__((ext_vector_type(4))) float f32x4;

#define DEVI __device__ __forceinline__

DEVI unsigned short f2bf(float f) {
  __hip_bfloat16 h = __float2bfloat16(f);
  return *reinterpret_cast<unsigned short*>(&h);
}

DEVI void gload16(const void* g, void* l) {
  __builtin_amdgcn_global_load_lds((const __attribute__((address_space(1))) void*)g,
                                   (__attribute__((address_space(3))) void*)l, 16, 0, 0);
}

// ---------------- weight fp32 -> bf16 ----------------
__global__ __launch_bounds__(256) void k_f2bf(const float* __restrict__ in,
                                              unsigned short* __restrict__ out, int n) {
  int i = blockIdx.x * 256 + threadIdx.x;
  if (i < n) out[i] = f2bf(in[i]);
}

// ---------------- LN1 + transpose: x[b][c][p] -> xt fp32 [tok][c], xln bf16 [tok][c] ----------------
__global__ __launch_bounds__(256) void k_ln1(const float* __restrict__ x,
                                             const float* __restrict__ g,
                                             const float* __restrict__ be,
                                             float* __restrict__ xt,
                                             unsigned short* __restrict__ xln) {
  __shared__ float tile[256][33];
  const int b  = blockIdx.y;
  const int p0 = blockIdx.x * 32;
  const int t  = threadIdx.x;
  const float* src = x + ((size_t)b * 256 + t) * 1024 + p0;
#pragma unroll
  for (int j = 0; j < 32; j += 4) {
    float4 v = *(const float4*)(src + j);
    tile[t][j] = v.x; tile[t][j + 1] = v.y; tile[t][j + 2] = v.z; tile[t][j + 3] = v.w;
  }
  __syncthreads();
  const int w = t >> 6, l = t & 63;
#pragma unroll
  for (int i = 0; i < 8; i++) {
    const int p = w * 8 + i;
    float s = 0.f, ss = 0.f;
#pragma unroll
    for (int q = 0; q < 4; q++) {
      float v = tile[l + 64 * q][p];
      s += v; ss += v * v;
    }
#pragma unroll
    for (int msk = 1; msk < 64; msk <<= 1) {
      s  += __shfl_xor(s, msk);
      ss += __shfl_xor(ss, msk);
    }
    const float mean = s * (1.f / 256.f);
    const float var  = ss * (1.f / 256.f) - mean * mean;
    const float rs   = rsqrtf(var + 1e-5f);
    const size_t token = (size_t)b * 1024 + p0 + p;
#pragma unroll
    for (int q = 0; q < 4; q++) {
      const int c = l + 64 * q;
      const float v = tile[c][p];
      xt[token * 256 + c]  = v;
      xln[token * 256 + c] = f2bf((v - mean) * rs * g[c] + be[c]);
    }
  }
}

// ---------------- GEMM: C[M,N] = A[M,K] @ B[N,K]^T, bf16 in, fp32 acc ----------------
// Double-buffered LDS, 1 barrier per k-step (loads for kt+1 fly under compute of kt).
// EPI 0: store bf16 to outb [gr][gc] for gc<512; for gc>=512 (V columns of qkv GEMM):
//        swapped-operand MFMA -> transposed fragment -> write vT[b][h][d][tok] coalesced.
template <int EPI, int NN>
__global__ __launch_bounds__(256) void k_gemm(const unsigned short* __restrict__ A, int lda,
                                              const unsigned short* __restrict__ Bw, int ldb,
                                              int K,
                                              const float* __restrict__ bias,
                                              const float* __restrict__ addend, int ldadd,
                                              float* __restrict__ outf,
                                              unsigned short* __restrict__ outb, int ldc,
                                              unsigned short* __restrict__ vtb) {
  __shared__ __align__(16) unsigned short As[2][128 * 64];
  __shared__ __align__(16) unsigned short Bs[2][128 * 64];
  const int nwg = gridDim.x;
  const int id  = (blockIdx.x & 7) * (nwg >> 3) + (blockIdx.x >> 3);
  const int m0  = (id / NN) * 128, n0 = (id % NN) * 128;
  const int t  = threadIdx.x;
  const int w  = t >> 6, l = t & 63;
  const int wm = (w >> 1) * 64, wn = (w & 1) * 64;
  const int lr = l & 15, hi = l >> 4, lk = hi * 8;
  const bool vsw = (EPI == 0) && (n0 >= 512);
  f32x4 acc[4][4] = {};
  const int nkt = K >> 6;
  const int e  = t * 8;
  const int er = e >> 6, ec = e & 63;

  // prologue: stage kt=0 into buf 0
#pragma unroll
  for (int i = 0; i < 4; i++) {
    gload16(&A[(size_t)(m0 + er + i * 32) * lda + ec], &As[0][e + i * 2048]);
    gload16(&Bw[(size_t)(n0 + er + i * 32) * ldb + ec], &Bs[0][e + i * 2048]);
  }

  for (int kt = 0; kt < nkt; ++kt) {
    const int cur = kt & 1;
    __syncthreads();  // drains vmcnt -> buf[cur] ready; all waves done reading buf[cur^1]
    if (kt + 1 < nkt) {
      const int kn = (kt + 1) * 64;
#pragma unroll
      for (int i = 0; i < 4; i++) {
        gload16(&A[(size_t)(m0 + er + i * 32) * lda + kn + ec], &As[cur ^ 1][e + i * 2048]);
        gload16(&Bw[(size_t)(n0 + er + i * 32) * ldb + kn + ec], &Bs[cur ^ 1][e + i * 2048]);
      }
    }
#pragma unroll
    for (int ks = 0; ks < 2; ks++) {
      bf16x8 af[4], bfr[4];
#pragma unroll
      for (int i = 0; i < 4; i++) af[i] = *(const bf16x8*)&As[cur][(wm + i * 16 + lr) * 64 + ks * 32 + lk];
#pragma unroll
      for (int j = 0; j < 4; j++) bfr[j] = *(const bf16x8*)&Bs[cur][(wn + j * 16 + lr) * 64 + ks * 32 + lk];
      if (vsw) {
#pragma unroll
        for (int i = 0; i < 4; i++)
#pragma unroll
          for (int j = 0; j < 4; j++)
            acc[i][j] = __builtin_amdgcn_mfma_f32_16x16x32_bf16(bfr[j], af[i], acc[i][j], 0, 0, 0);
      } else {
#pragma unroll
        for (int i = 0; i < 4; i++)
#pragma unroll
          for (int j = 0; j < 4; j++)
            acc[i][j] = __builtin_amdgcn_mfma_f32_16x16x32_bf16(af[i], bfr[j], acc[i][j], 0, 0, 0);
      }
    }
  }

  if (vsw) {
    // transposed fragment: r-dim -> gn (weight row / output channel), col -> gm (token)
#pragma unroll
    for (int i = 0; i < 4; i++)
#pragma unroll
      for (int j = 0; j < 4; j++)
#pragma unroll
        for (int r = 0; r < 4; r++) {
          const int gn = n0 + wn + j * 16 + hi * 4 + r;   // 512..767
          const int gm = m0 + wm + i * 16 + lr;           // token (all in one batch)
          const int c = gn - 512;
          const int b = gm >> 10;
          vtb[(size_t)(b * 256 + c) * 1024 + (gm & 1023)] = f2bf(acc[i][j][r]);
        }
    return;
  }
#pragma unroll
  for (int i = 0; i < 4; i++)
#pragma unroll
    for (int j = 0; j < 4; j++)
#pragma unroll
      for (int r = 0; r < 4; r++) {
        const int gr = m0 + wm + i * 16 + hi * 4 + r;
        const int gc = n0 + wn + j * 16 + lr;
        const float v = acc[i][j][r];
        if constexpr (EPI == 0) {
          outb[(size_t)gr * ldc + gc] = f2bf(v);
        } else if constexpr (EPI == 1) {
          outf[(size_t)gr * ldc + gc] = v + bias[gc] + addend[(size_t)gr * ldadd + gc];
        } else if constexpr (EPI == 2) {
          const float z = v + bias[gc];
          outb[(size_t)gr * ldc + gc] = f2bf(z > 0.f ? z : 0.f);
        } else {
          outf[(size_t)gr * ldc + gc] = v + bias[gc] + addend[(size_t)gr * ldadd + gc];
        }
      }
}

// ---------------- flash attention (swapped QK^T + defer-max, exp2, reg-prefetch) ----------------
// qkv bf16 [tok][512]: q at [h*32], k at [256+h*32].  vT bf16 [b*8+h][32 d][1024 tok].
// 1024 blocks (XCD-swizzled) x 256 thr: 8 q-tiles of 128 rows x 128 bh. wave = 32 q rows.
__global__ __launch_bounds__(256) void k_attn(const unsigned short* __restrict__ qkv,
                                              const unsigned short* __restrict__ vt,
                                              unsigned short* __restrict__ attn_out) {
  __shared__ __align__(16) unsigned short Ks[64][40];
  __shared__ __align__(16) unsigned short Vs[32][72];
  __shared__ __align__(16) unsigned short Pq[4][32][72];

  const int bid  = blockIdx.x;
  const int wgid = (bid & 7) * 128 + (bid >> 3);  // bijective (1024 % 8 == 0)
  const int bh = wgid >> 3;
  const int qt = wgid & 7;
  const int b = bh >> 3, h = bh & 7;
  const int q0 = qt * 128;
  const int t = threadIdx.x, w = t >> 6, l = t & 63;
  const int lr = l & 15, hi = l >> 4, lk = hi * 8;
  const size_t base  = (size_t)b * 1024 * 512;
  const size_t vbase = (size_t)bh * 32 * 1024;
  const float c2 = 1.4426950408889634f * 0.17677669529663687f;  // log2e/sqrt(32)

  bf16x8 qf[2];
#pragma unroll
  for (int qi = 0; qi < 2; qi++)
    qf[qi] = *(const bf16x8*)&qkv[base + (size_t)(q0 + w * 32 + qi * 16 + lr) * 512 + h * 32 + lk];

  f32x4 o[2][2] = {};
  float m2[2]   = {0.f, 0.f};
  float lsum[2] = {0.f, 0.f};
  const f32x4 z4 = {0.f, 0.f, 0.f, 0.f};

  // staging assignments
  const int stok = t >> 2;         // K: token 0..63
  const int sd0  = (t & 3) * 8;    // K: 8 d elems
  const int vsd  = t >> 3;         // V: d row 0..31
  const int vtk  = (t & 7) * 8;    // V: 8 tokens

  // prologue: load chunk 0 into regs
  bf16x8 nk = *(const bf16x8*)&qkv[base + (size_t)stok * 512 + 256 + h * 32 + sd0];
  bf16x8 nv = *(const bf16x8*)&vt[vbase + (size_t)vsd * 1024 + vtk];

  for (int kc = 0; kc < 16; kc++) {
    __syncthreads();  // previous chunk's LDS reads done
    *(bf16x8*)&Ks[stok][sd0] = nk;
    *(bf16x8*)&Vs[vsd][vtk]  = nv;
    __syncthreads();

    // issue next chunk's loads; latency hides under compute below
    {
      const int knx = ((kc + 1) & 15) * 64;
      nk = *(const bf16x8*)&qkv[base + (size_t)(knx + stok) * 512 + 256 + h * 32 + sd0];
      nv = *(const bf16x8*)&vt[vbase + (size_t)vsd * 1024 + knx + vtk];
    }

    bf16x8 kf[4];
#pragma unroll
    for (int blk = 0; blk < 4; blk++) kf[blk] = *(const bf16x8*)&Ks[blk * 16 + lr][lk];

#pragma unroll
    for (int qi = 0; qi < 2; qi++) {
      // St = K @ Q^T : lane holds score(q = lr, key = blk*16 + hi*4 + r)
      f32x4 s[4];
#pragma unroll
      for (int blk = 0; blk < 4; blk++)
        s[blk] = __builtin_amdgcn_mfma_f32_16x16x32_bf16(kf[blk], qf[qi], z4, 0, 0, 0);

      float pm = s[0][0];
#pragma unroll
      for (int blk = 0; blk < 4; blk++)
#pragma unroll
        for (int r = 0; r < 4; r++) pm = fmaxf(pm, s[blk][r]);

      if (!__all(pm * c2 <= m2[qi] + 11.54f)) {  // defer-max slow path
        float mx = pm;
        mx = fmaxf(mx, __shfl_xor(mx, 16));
        mx = fmaxf(mx, __shfl_xor(mx, 32));
        const float m2n = fmaxf(m2[qi], mx * c2);
        const float d2  = m2[qi] - m2n;
        lsum[qi] *= exp2f(d2);
#pragma unroll
        for (int r = 0; r < 4; r++) {
          const float a = exp2f(__shfl(d2, hi * 4 + r));
          o[qi][0][r] *= a; o[qi][1][r] *= a;
        }
        m2[qi] = m2n;
      }

      float ls = 0.f;
#pragma unroll
      for (int blk = 0; blk < 4; blk++) {
        const float p0 = exp2f(fmaf(s[blk][0], c2, -m2[qi]));
        const float p1 = exp2f(fmaf(s[blk][1], c2, -m2[qi]));
        const float p2 = exp2f(fmaf(s[blk][2], c2, -m2[qi]));
        const float p3 = exp2f(fmaf(s[blk][3], c2, -m2[qi]));
        ls += (p0 + p1) + (p2 + p3);
        ushort4 us;
        us.x = f2bf(p0); us.y = f2bf(p1); us.z = f2bf(p2); us.w = f2bf(p3);
        *(ushort4*)&Pq[w][qi * 16 + lr][blk * 16 + hi * 4] = us;
      }
      lsum[qi] += ls;
    }

    // O += P @ V : A = P[q][keys], B = Vs[d][keys]
#pragma unroll
    for (int ks = 0; ks < 2; ks++) {
      const bf16x8 v0f = *(const bf16x8*)&Vs[lr][ks * 32 + lk];
      const bf16x8 v1f = *(const bf16x8*)&Vs[16 + lr][ks * 32 + lk];
#pragma unroll
      for (int qi = 0; qi < 2; qi++) {
        const bf16x8 pa = *(const bf16x8*)&Pq[w][qi * 16 + lr][ks * 32 + lk];
        o[qi][0] = __builtin_amdgcn_mfma_f32_16x16x32_bf16(pa, v0f, o[qi][0], 0, 0, 0);
        o[qi][1] = __builtin_amdgcn_mfma_f32_16x16x32_bf16(pa, v1f, o[qi][1], 0, 0, 0);
      }
    }
  }

#pragma unroll
  for (int qi = 0; qi < 2; qi++) {
    float lsq = lsum[qi];
    lsq += __shfl_xor(lsq, 16);
    lsq += __shfl_xor(lsq, 32);
#pragma unroll
    for (int r = 0; r < 4; r++) {
      const int qloc = hi * 4 + r;
      const float inv = 1.f / __shfl(lsq, qloc);
      const int row = q0 + w * 32 + qi * 16 + qloc;
      attn_out[(size_t)(b * 1024 + row) * 256 + h * 32 + lr]      = f2bf(o[qi][0][r] * inv);
      attn_out[(size_t)(b * 1024 + row) * 256 + h * 32 + 16 + lr] = f2bf(o[qi][1][r] * inv);
    }
  }
}

// ---------------- LN2: y fp32 [tok][256] -> yln bf16 ----------------
__global__ __launch_bounds__(256) void k_ln2(const float* __restrict__ y,
                                             const float* __restrict__ g,
                                             const float* __restrict__ be,
                                             unsigned short* __restrict__ yln) {
  const int row = blockIdx.x * 4 + (threadIdx.x >> 6);
  const int l = threadIdx.x & 63;
  const float* yr = y + (size_t)row * 256;
  const float4 v = *(const float4*)(yr + l * 4);
  float s  = v.x + v.y + v.z + v.w;
  float ss = v.x * v.x + v.y * v.y + v.z * v.z + v.w * v.w;
#pragma unroll
  for (int msk = 1; msk < 64; msk <<= 1) {
    s  += __shfl_xor(s, msk);
    ss += __shfl_xor(ss, msk);
  }
  const float mean = s * (1.f / 256.f);
  const float var  = ss * (1.f / 256.f) - mean * mean;
  const float rs   = rsqrtf(var + 1e-5f);
  const float4 gv  = *(const float4*)(g + l * 4);
  const float4 bv  = *(const float4*)(be + l * 4);
  ushort4 o;
  o.x = f2bf((v.x - mean) * rs * gv.x + bv.x);
  o.y = f2bf((v.y - mean) * rs * gv.y + bv.y);
  o.z = f2bf((v.z - mean) * rs * gv.z + bv.z);
  o.w = f2bf((v.w - mean) * rs * gv.w + bv.w);
  *(ushort4*)&yln[(size_t)row * 256 + l * 4] = o;
}

// ---------------- output transpose: z[b][s][c] -> out[b][c][s] ----------------
__global__ __launch_bounds__(256) void k_tout(const float* __restrict__ z,
                                              float* __restrict__ out) {
  __shared__ float tile[32][33];
  const int b  = blockIdx.z;
  const int c0 = blockIdx.y * 32, p0 = blockIdx.x * 32;
  const int tx = threadIdx.x & 31, ty = threadIdx.x >> 5;
#pragma unroll
  for (int i = 0; i < 32; i += 8)
    tile[ty + i][tx] = z[((size_t)b * 1024 + p0 + ty + i) * 256 + c0 + tx];
  __syncthreads();
#pragma unroll
  for (int i = 0; i < 32; i += 8)
    out[((size_t)b * 256 + c0 + ty + i) * 1024 + p0 + tx] = tile[tx][ty + i];
}

// ---------------- launch ----------------
extern "C" void kernel_launch(void* const* d_in, const int* in_sizes, int n_in,
                              void* d_out, int out_size, void* d_ws, size_t ws_size,
                              hipStream_t stream) {
  const float* x      = (const float*)d_in[0];
  const float* w_qkv  = (const float*)d_in[1];
  const float* w_proj = (const float*)d_in[2];
  const float* b_proj = (const float*)d_in[3];
  const float* g1     = (const float*)d_in[4];
  const float* beta1  = (const float*)d_in[5];
  const float* g2     = (const float*)d_in[6];
  const float* beta2  = (const float*)d_in[7];
  const float* w1     = (const float*)d_in[8];
  const float* b1     = (const float*)d_in[9];
  const float* w2     = (const float*)d_in[10];
  const float* b2     = (const float*)d_in[11];
  float* out = (float*)d_out;
  char* ws = (char*)d_ws;

  constexpr size_t OFF_XT  = 0;                       // 16 MB fp32 [tok][256]
  constexpr size_t OFF_XLN = 16777216;                //  8 MB bf16
  constexpr size_t OFF_QKV = OFF_XLN + 8388608;       // 16 MB bf16 [tok][512] (Q,K only)
  constexpr size_t OFF_ATT = OFF_QKV + 16777216;      //  8 MB bf16
  constexpr size_t OFF_Y   = OFF_ATT + 8388608;       // 16 MB fp32 (aliases vT before GEMM<1>)
  constexpr size_t OFF_YLN = OFF_Y + 16777216;        //  8 MB bf16
  constexpr size_t OFF_W   = OFF_YLN + 8388608;       // weights bf16
  constexpr size_t OFF_H1  = OFF_XLN;                 // alias: 32 MB bf16 [tok][1024]
  constexpr size_t OFF_Z   = OFF_XT;                  // alias: 16 MB fp32
  constexpr size_t OFF_VT  = OFF_Y;                   // alias: 8 MB bf16 [bh][32][1024]

  float*          xt    = (float*)(ws + OFF_XT);
  unsigned short* xln   = (unsigned short*)(ws + OFF_XLN);
  unsigned short* qkv   = (unsigned short*)(ws + OFF_QKV);
  unsigned short* attn  = (unsigned short*)(ws + OFF_ATT);
  float*          y     = (float*)(ws + OFF_Y);
  unsigned short* yln   = (unsigned short*)(ws + OFF_YLN);
  unsigned short* h1    = (unsigned short*)(ws + OFF_H1);
  float*          z     = (float*)(ws + OFF_Z);
  unsigned short* vtb   = (unsigned short*)(ws + OFF_VT);
  unsigned short* wqkvb = (unsigned short*)(ws + OFF_W);
  unsigned short* wprjb = (unsigned short*)(ws + OFF_W + 393216);
  unsigned short* w1b   = (unsigned short*)(ws + OFF_W + 393216 + 131072);
  unsigned short* w2b   = (unsigned short*)(ws + OFF_W + 393216 + 131072 + 524288);

  k_f2bf<<<768, 256, 0, stream>>>(w_qkv, wqkvb, 768 * 256);
  k_f2bf<<<256, 256, 0, stream>>>(w_proj, wprjb, 256 * 256);
  k_f2bf<<<1024, 256, 0, stream>>>(w1, w1b, 1024 * 256);
  k_f2bf<<<1024, 256, 0, stream>>>(w2, w2b, 256 * 1024);

  k_ln1<<<dim3(32, 16), 256, 0, stream>>>(x, g1, beta1, xt, xln);

  // qkv = xln @ w_qkv^T : Q,K -> qkv[tok][512]; V -> vT[bh][d][tok]
  k_gemm<0, 6><<<768, 256, 0, stream>>>(xln, 256, wqkvb, 256, 256,
                                        nullptr, nullptr, 0, nullptr, qkv, 512, vtb);

  k_attn<<<1024, 256, 0, stream>>>(qkv, vtb, attn);

  // y = attn @ w_proj^T + b_proj + xt
  k_gemm<1, 2><<<256, 256, 0, stream>>>(attn, 256, wprjb, 256, 256,
                                        b_proj, xt, 256, y, nullptr, 256, nullptr);

  k_ln2<<<4096, 256, 0, stream>>>(y, g2, beta2, yln);

  // h1 = relu(yln @ w1^T + b1)
  k_gemm<2, 8><<<1024, 256, 0, stream>>>(yln, 256, w1b, 256, 256,
                                         b1, nullptr, 0, nullptr, h1, 1024, nullptr);

  // z = h1 @ w2^T + b2 + y
  k_gemm<3, 2><<<256, 256, 0, stream>>>(h1, 1024, w2b, 1024, 1024,
                                        b2, y, 256, z, nullptr, 256, nullptr);

  k_tout<<<dim3(32, 8, 16), 256, 0, stream>>>(z, out);
}

// Round 5
// 144.655 us; speedup vs baseline: 1.2987x; 1.1474x over previous
//
#include <hip/hip_runtime.h>
#include <hip/hip_bf16.h>

typedef __attribute__((ext_vector_type(8))) short bf16x8;
typedef __attribute__((ext_vector_type(4))) float f32x4;

#define DEVI __device__ __forceinline__

DEVI unsigned short f2bf(float f) {
  __hip_bfloat16 h = __float2bfloat16(f);
  return *reinterpret_cast<unsigned short*>(&h);
}

DEVI void gload16(const void* g, void* l) {
  __builtin_amdgcn_global_load_lds((const __attribute__((address_space(1))) void*)g,
                                   (__attribute__((address_space(3))) void*)l, 16, 0, 0);
}

DEVI float max4(const f32x4 v) {
  return fmaxf(fmaxf(v[0], v[1]), fmaxf(v[2], v[3]));
}

// ---------------- fused weight casts fp32 -> bf16 (float4 vectorized) ----------------
__global__ __launch_bounds__(256) void k_casts(const float* __restrict__ a, const float* __restrict__ b,
                                               const float* __restrict__ c, const float* __restrict__ d,
                                               unsigned short* __restrict__ oa, unsigned short* __restrict__ ob,
                                               unsigned short* __restrict__ oc, unsigned short* __restrict__ od) {
  const int i4 = (blockIdx.x * 256 + threadIdx.x) * 4;
  const float* src; unsigned short* dst; int off;
  if (i4 < 196608)      { src = a; dst = oa; off = 0; }
  else if (i4 < 262144) { src = b; dst = ob; off = 196608; }
  else if (i4 < 524288) { src = c; dst = oc; off = 262144; }
  else                  { src = d; dst = od; off = 524288; }
  const int j = i4 - off;
  const float4 v = *(const float4*)(src + j);
  ushort4 o;
  o.x = f2bf(v.x); o.y = f2bf(v.y); o.z = f2bf(v.z); o.w = f2bf(v.w);
  *(ushort4*)(dst + j) = o;
}

// ---------------- LN1 + transpose: x[b][c][p] -> xt fp32 [tok][c], xln bf16 [tok][c] ----------------
__global__ __launch_bounds__(256) void k_ln1(const float* __restrict__ x,
                                             const float* __restrict__ g,
                                             const float* __restrict__ be,
                                             float* __restrict__ xt,
                                             unsigned short* __restrict__ xln) {
  __shared__ float tile[256][33];
  const int b  = blockIdx.y;
  const int p0 = blockIdx.x * 32;
  const int t  = threadIdx.x;
  const float* src = x + ((size_t)b * 256 + t) * 1024 + p0;
#pragma unroll
  for (int j = 0; j < 32; j += 4) {
    float4 v = *(const float4*)(src + j);
    tile[t][j] = v.x; tile[t][j + 1] = v.y; tile[t][j + 2] = v.z; tile[t][j + 3] = v.w;
  }
  __syncthreads();
  const int w = t >> 6, l = t & 63;
#pragma unroll
  for (int i = 0; i < 8; i++) {
    const int p = w * 8 + i;
    float s = 0.f, ss = 0.f;
#pragma unroll
    for (int q = 0; q < 4; q++) {
      float v = tile[l + 64 * q][p];
      s += v; ss += v * v;
    }
#pragma unroll
    for (int msk = 1; msk < 64; msk <<= 1) {
      s  += __shfl_xor(s, msk);
      ss += __shfl_xor(ss, msk);
    }
    const float mean = s * (1.f / 256.f);
    const float var  = ss * (1.f / 256.f) - mean * mean;
    const float rs   = rsqrtf(var + 1e-5f);
    const size_t token = (size_t)b * 1024 + p0 + p;
#pragma unroll
    for (int q = 0; q < 4; q++) {
      const int c = l + 64 * q;
      const float v = tile[c][p];
      xt[token * 256 + c]  = v;
      xln[token * 256 + c] = f2bf((v - mean) * rs * g[c] + be[c]);
    }
  }
}

// ---------------- GEMM: C[M,N] = A[M,K] @ B[N,K]^T, bf16 in, fp32 acc ----------------
// Double-buffered LDS, 1 barrier per k-step.
// EPI 0: store bf16 (qkv); n0>=512 (V cols): swapped MFMA -> vT[bh][d][tok]
// EPI 1: +bias +addend -> f32 (proj + residual)
// EPI 2: +bias, relu -> bf16 (ffn1)
// EPI 3: swapped MFMA; +bias +addend(y[tok][c]) -> out[b][c][s] directly (folds k_tout)
template <int EPI, int NN>
__global__ __launch_bounds__(256) void k_gemm(const unsigned short* __restrict__ A, int lda,
                                              const unsigned short* __restrict__ Bw, int ldb,
                                              int K,
                                              const float* __restrict__ bias,
                                              const float* __restrict__ addend, int ldadd,
                                              float* __restrict__ outf,
                                              unsigned short* __restrict__ outb, int ldc,
                                              unsigned short* __restrict__ vtb) {
  __shared__ __align__(16) unsigned short As[2][128 * 64];
  __shared__ __align__(16) unsigned short Bs[2][128 * 64];
  const int nwg = gridDim.x;
  const int id  = (blockIdx.x & 7) * (nwg >> 3) + (blockIdx.x >> 3);
  const int m0  = (id / NN) * 128, n0 = (id % NN) * 128;
  const int t  = threadIdx.x;
  const int w  = t >> 6, l = t & 63;
  const int wm = (w >> 1) * 64, wn = (w & 1) * 64;
  const int lr = l & 15, hi = l >> 4, lk = hi * 8;
  const bool swp = (EPI == 3) || ((EPI == 0) && (n0 >= 512));
  f32x4 acc[4][4] = {};
  const int nkt = K >> 6;
  const int e  = t * 8;
  const int er = e >> 6, ec = e & 63;

#pragma unroll
  for (int i = 0; i < 4; i++) {
    gload16(&A[(size_t)(m0 + er + i * 32) * lda + ec], &As[0][e + i * 2048]);
    gload16(&Bw[(size_t)(n0 + er + i * 32) * ldb + ec], &Bs[0][e + i * 2048]);
  }

  for (int kt = 0; kt < nkt; ++kt) {
    const int cur = kt & 1;
    __syncthreads();  // drains vmcnt -> buf[cur] ready; all waves done with buf[cur^1]
    if (kt + 1 < nkt) {
      const int kn = (kt + 1) * 64;
#pragma unroll
      for (int i = 0; i < 4; i++) {
        gload16(&A[(size_t)(m0 + er + i * 32) * lda + kn + ec], &As[cur ^ 1][e + i * 2048]);
        gload16(&Bw[(size_t)(n0 + er + i * 32) * ldb + kn + ec], &Bs[cur ^ 1][e + i * 2048]);
      }
    }
#pragma unroll
    for (int ks = 0; ks < 2; ks++) {
      bf16x8 af[4], bfr[4];
#pragma unroll
      for (int i = 0; i < 4; i++) af[i] = *(const bf16x8*)&As[cur][(wm + i * 16 + lr) * 64 + ks * 32 + lk];
#pragma unroll
      for (int j = 0; j < 4; j++) bfr[j] = *(const bf16x8*)&Bs[cur][(wn + j * 16 + lr) * 64 + ks * 32 + lk];
      if (swp) {
#pragma unroll
        for (int i = 0; i < 4; i++)
#pragma unroll
          for (int j = 0; j < 4; j++)
            acc[i][j] = __builtin_amdgcn_mfma_f32_16x16x32_bf16(bfr[j], af[i], acc[i][j], 0, 0, 0);
      } else {
#pragma unroll
        for (int i = 0; i < 4; i++)
#pragma unroll
          for (int j = 0; j < 4; j++)
            acc[i][j] = __builtin_amdgcn_mfma_f32_16x16x32_bf16(af[i], bfr[j], acc[i][j], 0, 0, 0);
      }
    }
  }

  if constexpr (EPI == 3) {
    // transposed fragment: r -> channel, lr -> token; write out[b][c][s] directly
#pragma unroll
    for (int i = 0; i < 4; i++)
#pragma unroll
      for (int j = 0; j < 4; j++)
#pragma unroll
        for (int r = 0; r < 4; r++) {
          const int c  = n0 + wn + j * 16 + hi * 4 + r;
          const int gm = m0 + wm + i * 16 + lr;
          const int b  = gm >> 10, sI = gm & 1023;
          outf[((size_t)b * 256 + c) * 1024 + sI] =
              acc[i][j][r] + bias[c] + addend[(size_t)gm * 256 + c];
        }
    return;
  }
  if ((EPI == 0) && (n0 >= 512)) {
#pragma unroll
    for (int i = 0; i < 4; i++)
#pragma unroll
      for (int j = 0; j < 4; j++)
#pragma unroll
        for (int r = 0; r < 4; r++) {
          const int gn = n0 + wn + j * 16 + hi * 4 + r;   // 512..767
          const int gm = m0 + wm + i * 16 + lr;           // token
          const int c = gn - 512;
          const int b = gm >> 10;
          vtb[(size_t)(b * 256 + c) * 1024 + (gm & 1023)] = f2bf(acc[i][j][r]);
        }
    return;
  }
#pragma unroll
  for (int i = 0; i < 4; i++)
#pragma unroll
    for (int j = 0; j < 4; j++)
#pragma unroll
      for (int r = 0; r < 4; r++) {
        const int gr = m0 + wm + i * 16 + hi * 4 + r;
        const int gc = n0 + wn + j * 16 + lr;
        const float v = acc[i][j][r];
        if constexpr (EPI == 0) {
          outb[(size_t)gr * ldc + gc] = f2bf(v);
        } else if constexpr (EPI == 1) {
          outf[(size_t)gr * ldc + gc] = v + bias[gc] + addend[(size_t)gr * ldadd + gc];
        } else if constexpr (EPI == 2) {
          const float z = v + bias[gc];
          outb[(size_t)gr * ldc + gc] = f2bf(z > 0.f ? z : 0.f);
        }
      }
}

// ---------------- flash attention (swapped QK^T + defer-max, __expf, reg-prefetch) ----------------
// qkv bf16 [tok][512]: q at [h*32], k at [256+h*32].  vT bf16 [b*8+h][32 d][1024 tok].
// 1024 blocks (XCD-swizzled) x 256 thr: 8 q-tiles of 128 rows x 128 bh. wave = 32 q rows.
__global__ __launch_bounds__(256) void k_attn(const unsigned short* __restrict__ qkv,
                                              const unsigned short* __restrict__ vt,
                                              unsigned short* __restrict__ attn_out) {
  __shared__ __align__(16) unsigned short Ks[64][40];
  __shared__ __align__(16) unsigned short Vs[32][72];
  __shared__ __align__(16) unsigned short Pq[4][32][72];

  const int bid  = blockIdx.x;
  const int wgid = (bid & 7) * 128 + (bid >> 3);  // bijective (1024 % 8 == 0)
  const int bh = wgid >> 3;
  const int qt = wgid & 7;
  const int b = bh >> 3, h = bh & 7;
  const int q0 = qt * 128;
  const int t = threadIdx.x, w = t >> 6, l = t & 63;
  const int lr = l & 15, hi = l >> 4, lk = hi * 8;
  const size_t base  = (size_t)b * 1024 * 512;
  const size_t vbase = (size_t)bh * 32 * 1024;
  const float sc = 0.17677669529663687f;  // 1/sqrt(32)

  bf16x8 qf[2];
#pragma unroll
  for (int qi = 0; qi < 2; qi++)
    qf[qi] = *(const bf16x8*)&qkv[base + (size_t)(q0 + w * 32 + qi * 16 + lr) * 512 + h * 32 + lk];

  f32x4 o[2][2] = {};
  float m[2]    = {0.f, 0.f};
  float lsum[2] = {0.f, 0.f};
  const f32x4 z4 = {0.f, 0.f, 0.f, 0.f};

  const int stok = t >> 2;         // K: token 0..63
  const int sd0  = (t & 3) * 8;    // K: 8 d elems
  const int vsd  = t >> 3;         // V: d row 0..31
  const int vtk  = (t & 7) * 8;    // V: 8 tokens

  const unsigned short* pk = &qkv[base + (size_t)stok * 512 + 256 + h * 32 + sd0];
  const unsigned short* pv = &vt[vbase + (size_t)vsd * 1024 + vtk];
  bf16x8 nk = *(const bf16x8*)pk;
  bf16x8 nv = *(const bf16x8*)pv;

  for (int kc = 0; kc < 16; kc++) {
    __syncthreads();  // previous chunk's LDS reads done
    *(bf16x8*)&Ks[stok][sd0] = nk;
    *(bf16x8*)&Vs[vsd][vtk]  = nv;
    __syncthreads();

    if (kc < 15) {  // issue next chunk's loads; latency hides under compute
      pk += 64 * 512;
      pv += 64;
      nk = *(const bf16x8*)pk;
      nv = *(const bf16x8*)pv;
    }

    bf16x8 kf[4];
#pragma unroll
    for (int blk = 0; blk < 4; blk++) kf[blk] = *(const bf16x8*)&Ks[blk * 16 + lr][lk];

#pragma unroll
    for (int qi = 0; qi < 2; qi++) {
      // St = K @ Q^T : lane holds score(q = lr, key = blk*16 + hi*4 + r)
      f32x4 s[4];
#pragma unroll
      for (int blk = 0; blk < 4; blk++)
        s[blk] = __builtin_amdgcn_mfma_f32_16x16x32_bf16(kf[blk], qf[qi], z4, 0, 0, 0);

      // tree max (depth ~5, not a 31-deep serial chain)
      const float pm = fmaxf(fmaxf(max4(s[0]), max4(s[1])), fmaxf(max4(s[2]), max4(s[3])));

      if (!__all(pm * sc <= m[qi] + 8.f)) {  // defer-max slow path (rare)
        float mx = pm;
        mx = fmaxf(mx, __shfl_xor(mx, 16));
        mx = fmaxf(mx, __shfl_xor(mx, 32));
        const float mn = fmaxf(m[qi], mx * sc);
        const float d  = m[qi] - mn;
        lsum[qi] *= __expf(d);
#pragma unroll
        for (int r = 0; r < 4; r++) {
          const float a = __expf(__shfl(d, hi * 4 + r));
          o[qi][0][r] *= a; o[qi][1][r] *= a;
        }
        m[qi] = mn;
      }

      const float nm = -m[qi];
      float ls = 0.f;
#pragma unroll
      for (int blk = 0; blk < 4; blk++) {
        const float p0 = __expf(fmaf(s[blk][0], sc, nm));
        const float p1 = __expf(fmaf(s[blk][1], sc, nm));
        const float p2 = __expf(fmaf(s[blk][2], sc, nm));
        const float p3 = __expf(fmaf(s[blk][3], sc, nm));
        ls += (p0 + p1) + (p2 + p3);
        ushort4 us;
        us.x = f2bf(p0); us.y = f2bf(p1); us.z = f2bf(p2); us.w = f2bf(p3);
        *(ushort4*)&Pq[w][qi * 16 + lr][blk * 16 + hi * 4] = us;
      }
      lsum[qi] += ls;
    }

    // O += P @ V : A = P[q][keys], B = Vs[d][keys]
#pragma unroll
    for (int ks = 0; ks < 2; ks++) {
      const bf16x8 v0f = *(const bf16x8*)&Vs[lr][ks * 32 + lk];
      const bf16x8 v1f = *(const bf16x8*)&Vs[16 + lr][ks * 32 + lk];
#pragma unroll
      for (int qi = 0; qi < 2; qi++) {
        const bf16x8 pa = *(const bf16x8*)&Pq[w][qi * 16 + lr][ks * 32 + lk];
        o[qi][0] = __builtin_amdgcn_mfma_f32_16x16x32_bf16(pa, v0f, o[qi][0], 0, 0, 0);
        o[qi][1] = __builtin_amdgcn_mfma_f32_16x16x32_bf16(pa, v1f, o[qi][1], 0, 0, 0);
      }
    }
  }

#pragma unroll
  for (int qi = 0; qi < 2; qi++) {
    float lsq = lsum[qi];
    lsq += __shfl_xor(lsq, 16);
    lsq += __shfl_xor(lsq, 32);
#pragma unroll
    for (int r = 0; r < 4; r++) {
      const int qloc = hi * 4 + r;
      const float inv = 1.f / __shfl(lsq, qloc);
      const int row = q0 + w * 32 + qi * 16 + qloc;
      attn_out[(size_t)(b * 1024 + row) * 256 + h * 32 + lr]      = f2bf(o[qi][0][r] * inv);
      attn_out[(size_t)(b * 1024 + row) * 256 + h * 32 + 16 + lr] = f2bf(o[qi][1][r] * inv);
    }
  }
}

// ---------------- LN2: y fp32 [tok][256] -> yln bf16 ----------------
__global__ __launch_bounds__(256) void k_ln2(const float* __restrict__ y,
                                             const float* __restrict__ g,
                                             const float* __restrict__ be,
                                             unsigned short* __restrict__ yln) {
  const int row = blockIdx.x * 4 + (threadIdx.x >> 6);
  const int l = threadIdx.x & 63;
  const float* yr = y + (size_t)row * 256;
  const float4 v = *(const float4*)(yr + l * 4);
  float s  = v.x + v.y + v.z + v.w;
  float ss = v.x * v.x + v.y * v.y + v.z * v.z + v.w * v.w;
#pragma unroll
  for (int msk = 1; msk < 64; msk <<= 1) {
    s  += __shfl_xor(s, msk);
    ss += __shfl_xor(ss, msk);
  }
  const float mean = s * (1.f / 256.f);
  const float var  = ss * (1.f / 256.f) - mean * mean;
  const float rs   = rsqrtf(var + 1e-5f);
  const float4 gv  = *(const float4*)(g + l * 4);
  const float4 bv  = *(const float4*)(be + l * 4);
  ushort4 o;
  o.x = f2bf((v.x - mean) * rs * gv.x + bv.x);
  o.y = f2bf((v.y - mean) * rs * gv.y + bv.y);
  o.z = f2bf((v.z - mean) * rs * gv.z + bv.z);
  o.w = f2bf((v.w - mean) * rs * gv.w + bv.w);
  *(ushort4*)&yln[(size_t)row * 256 + l * 4] = o;
}

// ---------------- launch ----------------
extern "C" void kernel_launch(void* const* d_in, const int* in_sizes, int n_in,
                              void* d_out, int out_size, void* d_ws, size_t ws_size,
                              hipStream_t stream) {
  const float* x      = (const float*)d_in[0];
  const float* w_qkv  = (const float*)d_in[1];
  const float* w_proj = (const float*)d_in[2];
  const float* b_proj = (const float*)d_in[3];
  const float* g1     = (const float*)d_in[4];
  const float* beta1  = (const float*)d_in[5];
  const float* g2     = (const float*)d_in[6];
  const float* beta2  = (const float*)d_in[7];
  const float* w1     = (const float*)d_in[8];
  const float* b1     = (const float*)d_in[9];
  const float* w2     = (const float*)d_in[10];
  const float* b2     = (const float*)d_in[11];
  float* out = (float*)d_out;
  char* ws = (char*)d_ws;

  constexpr size_t OFF_XT  = 0;                       // 16 MB fp32 [tok][256]
  constexpr size_t OFF_XLN = 16777216;                //  8 MB bf16
  constexpr size_t OFF_QKV = OFF_XLN + 8388608;       // 16 MB bf16 [tok][512] (Q,K only)
  constexpr size_t OFF_ATT = OFF_QKV + 16777216;      //  8 MB bf16
  constexpr size_t OFF_Y   = OFF_ATT + 8388608;       // 16 MB fp32 (aliases vT before GEMM<1>)
  constexpr size_t OFF_YLN = OFF_Y + 16777216;        //  8 MB bf16
  constexpr size_t OFF_W   = OFF_YLN + 8388608;       // weights bf16
  constexpr size_t OFF_H1  = OFF_XLN;                 // alias: 32 MB bf16 [tok][1024]
  constexpr size_t OFF_VT  = OFF_Y;                   // alias: 8 MB bf16 [bh][32][1024]

  float*          xt    = (float*)(ws + OFF_XT);
  unsigned short* xln   = (unsigned short*)(ws + OFF_XLN);
  unsigned short* qkv   = (unsigned short*)(ws + OFF_QKV);
  unsigned short* attn  = (unsigned short*)(ws + OFF_ATT);
  float*          y     = (float*)(ws + OFF_Y);
  unsigned short* yln   = (unsigned short*)(ws + OFF_YLN);
  unsigned short* h1    = (unsigned short*)(ws + OFF_H1);
  unsigned short* vtb   = (unsigned short*)(ws + OFF_VT);
  unsigned short* wqkvb = (unsigned short*)(ws + OFF_W);
  unsigned short* wprjb = (unsigned short*)(ws + OFF_W + 393216);
  unsigned short* w1b   = (unsigned short*)(ws + OFF_W + 393216 + 131072);
  unsigned short* w2b   = (unsigned short*)(ws + OFF_W + 393216 + 131072 + 524288);

  k_casts<<<768, 256, 0, stream>>>(w_qkv, w_proj, w1, w2, wqkvb, wprjb, w1b, w2b);

  k_ln1<<<dim3(32, 16), 256, 0, stream>>>(x, g1, beta1, xt, xln);

  // qkv = xln @ w_qkv^T : Q,K -> qkv[tok][512]; V -> vT[bh][d][tok]
  k_gemm<0, 6><<<768, 256, 0, stream>>>(xln, 256, wqkvb, 256, 256,
                                        nullptr, nullptr, 0, nullptr, qkv, 512, vtb);

  k_attn<<<1024, 256, 0, stream>>>(qkv, vtb, attn);

  // y = attn @ w_proj^T + b_proj + xt
  k_gemm<1, 2><<<256, 256, 0, stream>>>(attn, 256, wprjb, 256, 256,
                                        b_proj, xt, 256, y, nullptr, 256, nullptr);

  k_ln2<<<4096, 256, 0, stream>>>(y, g2, beta2, yln);

  // h1 = relu(yln @ w1^T + b1)
  k_gemm<2, 8><<<1024, 256, 0, stream>>>(yln, 256, w1b, 256, 256,
                                         b1, nullptr, 0, nullptr, h1, 1024, nullptr);

  // out = transpose(h1 @ w2^T + b2 + y)  (direct [b][c][s] write)
  k_gemm<3, 2><<<256, 256, 0, stream>>>(h1, 1024, w2b, 1024, 1024,
                                        b2, y, 256, out, nullptr, 256, nullptr);
}

// Round 6
// 142.692 us; speedup vs baseline: 1.3165x; 1.0138x over previous
//
#include <hip/hip_runtime.h>
#include <hip/hip_bf16.h>

typedef __attribute__((ext_vector_type(8))) short bf16x8;
typedef __attribute__((ext_vector_type(4))) float f32x4;

#define DEVI __device__ __forceinline__

DEVI unsigned short f2bf(float f) {
  __hip_bfloat16 h = __float2bfloat16(f);
  return *reinterpret_cast<unsigned short*>(&h);
}

DEVI void gload16(const void* g, void* l) {
  __builtin_amdgcn_global_load_lds((const __attribute__((address_space(1))) void*)g,
                                   (__attribute__((address_space(3))) void*)l, 16, 0, 0);
}

DEVI float max4(const f32x4 v) {
  return fmaxf(fmaxf(v[0], v[1]), fmaxf(v[2], v[3]));
}

// ---------------- fused weight casts fp32 -> bf16 (float4 vectorized) ----------------
__global__ __launch_bounds__(256) void k_casts(const float* __restrict__ a, const float* __restrict__ b,
                                               const float* __restrict__ c, const float* __restrict__ d,
                                               unsigned short* __restrict__ oa, unsigned short* __restrict__ ob,
                                               unsigned short* __restrict__ oc, unsigned short* __restrict__ od) {
  const int i4 = (blockIdx.x * 256 + threadIdx.x) * 4;
  const float* src; unsigned short* dst; int off;
  if (i4 < 196608)      { src = a; dst = oa; off = 0; }
  else if (i4 < 262144) { src = b; dst = ob; off = 196608; }
  else if (i4 < 524288) { src = c; dst = oc; off = 262144; }
  else                  { src = d; dst = od; off = 524288; }
  const int j = i4 - off;
  const float4 v = *(const float4*)(src + j);
  ushort4 o;
  o.x = f2bf(v.x); o.y = f2bf(v.y); o.z = f2bf(v.z); o.w = f2bf(v.w);
  *(ushort4*)(dst + j) = o;
}

// ---------------- LN1 + transpose: x[b][c][p] -> xt fp32 [tok][c], xln bf16 [tok][c] ----------------
__global__ __launch_bounds__(256) void k_ln1(const float* __restrict__ x,
                                             const float* __restrict__ g,
                                             const float* __restrict__ be,
                                             float* __restrict__ xt,
                                             unsigned short* __restrict__ xln) {
  __shared__ float tile[256][33];
  const int b  = blockIdx.y;
  const int p0 = blockIdx.x * 32;
  const int t  = threadIdx.x;
  const float* src = x + ((size_t)b * 256 + t) * 1024 + p0;
#pragma unroll
  for (int j = 0; j < 32; j += 4) {
    float4 v = *(const float4*)(src + j);
    tile[t][j] = v.x; tile[t][j + 1] = v.y; tile[t][j + 2] = v.z; tile[t][j + 3] = v.w;
  }
  __syncthreads();
  const int w = t >> 6, l = t & 63;
#pragma unroll
  for (int i = 0; i < 8; i++) {
    const int p = w * 8 + i;
    float s = 0.f, ss = 0.f;
#pragma unroll
    for (int q = 0; q < 4; q++) {
      float v = tile[l + 64 * q][p];
      s += v; ss += v * v;
    }
#pragma unroll
    for (int msk = 1; msk < 64; msk <<= 1) {
      s  += __shfl_xor(s, msk);
      ss += __shfl_xor(ss, msk);
    }
    const float mean = s * (1.f / 256.f);
    const float var  = ss * (1.f / 256.f) - mean * mean;
    const float rs   = rsqrtf(var + 1e-5f);
    const size_t token = (size_t)b * 1024 + p0 + p;
#pragma unroll
    for (int q = 0; q < 4; q++) {
      const int c = l + 64 * q;
      const float v = tile[c][p];
      xt[token * 256 + c]  = v;
      xln[token * 256 + c] = f2bf((v - mean) * rs * g[c] + be[c]);
    }
  }
}

// ---------------- GEMM: C[M,N] = A[M,K] @ B[N,K]^T, bf16 in, fp32 acc ----------------
// Double-buffered LDS, 1 barrier per k-step. BM in {64,128}, BN=128.
// EPI 0: store bf16 (qkv); n0>=512 (V cols): swapped MFMA -> vT[bh][d][tok]
// EPI 1: +bias +addend -> f32 (proj + residual)
// EPI 2: +bias, relu -> bf16 (ffn1)
// EPI 3: swapped MFMA; +bias +addend(y[tok][c]) -> out[b][c][s] directly (folds k_tout)
template <int EPI, int NN, int BM>
__global__ __launch_bounds__(256) void k_gemm(const unsigned short* __restrict__ A, int lda,
                                              const unsigned short* __restrict__ Bw, int ldb,
                                              int K,
                                              const float* __restrict__ bias,
                                              const float* __restrict__ addend, int ldadd,
                                              float* __restrict__ outf,
                                              unsigned short* __restrict__ outb, int ldc,
                                              unsigned short* __restrict__ vtb) {
  constexpr int MI = BM / 32;        // acc frag-rows per wave
  constexpr int IA = (BM * 64) / 2048;  // A staging iterations
  __shared__ __align__(16) unsigned short As[2][BM * 64];
  __shared__ __align__(16) unsigned short Bs[2][128 * 64];
  const int nwg = gridDim.x;
  const int id  = (blockIdx.x & 7) * (nwg >> 3) + (blockIdx.x >> 3);
  const int m0  = (id / NN) * BM, n0 = (id % NN) * 128;
  const int t  = threadIdx.x;
  const int w  = t >> 6, l = t & 63;
  const int wm = (w >> 1) * (BM / 2), wn = (w & 1) * 64;
  const int lr = l & 15, hi = l >> 4, lk = hi * 8;
  const bool swp = (EPI == 3) || ((EPI == 0) && (n0 >= 512));
  f32x4 acc[MI][4] = {};
  const int nkt = K >> 6;
  const int e  = t * 8;
  const int er = e >> 6, ec = e & 63;

#pragma unroll
  for (int i = 0; i < IA; i++)
    gload16(&A[(size_t)(m0 + er + i * 32) * lda + ec], &As[0][e + i * 2048]);
#pragma unroll
  for (int i = 0; i < 4; i++)
    gload16(&Bw[(size_t)(n0 + er + i * 32) * ldb + ec], &Bs[0][e + i * 2048]);

  for (int kt = 0; kt < nkt; ++kt) {
    const int cur = kt & 1;
    __syncthreads();  // drains vmcnt -> buf[cur] ready; all waves done with buf[cur^1]
    if (kt + 1 < nkt) {
      const int kn = (kt + 1) * 64;
#pragma unroll
      for (int i = 0; i < IA; i++)
        gload16(&A[(size_t)(m0 + er + i * 32) * lda + kn + ec], &As[cur ^ 1][e + i * 2048]);
#pragma unroll
      for (int i = 0; i < 4; i++)
        gload16(&Bw[(size_t)(n0 + er + i * 32) * ldb + kn + ec], &Bs[cur ^ 1][e + i * 2048]);
    }
#pragma unroll
    for (int ks = 0; ks < 2; ks++) {
      bf16x8 af[MI], bfr[4];
#pragma unroll
      for (int i = 0; i < MI; i++) af[i] = *(const bf16x8*)&As[cur][(wm + i * 16 + lr) * 64 + ks * 32 + lk];
#pragma unroll
      for (int j = 0; j < 4; j++) bfr[j] = *(const bf16x8*)&Bs[cur][(wn + j * 16 + lr) * 64 + ks * 32 + lk];
      if (swp) {
#pragma unroll
        for (int i = 0; i < MI; i++)
#pragma unroll
          for (int j = 0; j < 4; j++)
            acc[i][j] = __builtin_amdgcn_mfma_f32_16x16x32_bf16(bfr[j], af[i], acc[i][j], 0, 0, 0);
      } else {
#pragma unroll
        for (int i = 0; i < MI; i++)
#pragma unroll
          for (int j = 0; j < 4; j++)
            acc[i][j] = __builtin_amdgcn_mfma_f32_16x16x32_bf16(af[i], bfr[j], acc[i][j], 0, 0, 0);
      }
    }
  }

  if constexpr (EPI == 3) {
    // transposed fragment: r -> channel, lr -> token; write out[b][c][s] directly
#pragma unroll
    for (int i = 0; i < MI; i++)
#pragma unroll
      for (int j = 0; j < 4; j++)
#pragma unroll
        for (int r = 0; r < 4; r++) {
          const int c  = n0 + wn + j * 16 + hi * 4 + r;
          const int gm = m0 + wm + i * 16 + lr;
          const int b  = gm >> 10, sI = gm & 1023;
          outf[((size_t)b * 256 + c) * 1024 + sI] =
              acc[i][j][r] + bias[c] + addend[(size_t)gm * 256 + c];
        }
    return;
  }
  if ((EPI == 0) && (n0 >= 512)) {
#pragma unroll
    for (int i = 0; i < MI; i++)
#pragma unroll
      for (int j = 0; j < 4; j++)
#pragma unroll
        for (int r = 0; r < 4; r++) {
          const int gn = n0 + wn + j * 16 + hi * 4 + r;   // 512..767
          const int gm = m0 + wm + i * 16 + lr;           // token
          const int c = gn - 512;
          const int b = gm >> 10;
          vtb[(size_t)(b * 256 + c) * 1024 + (gm & 1023)] = f2bf(acc[i][j][r]);
        }
    return;
  }
#pragma unroll
  for (int i = 0; i < MI; i++)
#pragma unroll
    for (int j = 0; j < 4; j++)
#pragma unroll
      for (int r = 0; r < 4; r++) {
        const int gr = m0 + wm + i * 16 + hi * 4 + r;
        const int gc = n0 + wn + j * 16 + lr;
        const float v = acc[i][j][r];
        if constexpr (EPI == 0) {
          outb[(size_t)gr * ldc + gc] = f2bf(v);
        } else if constexpr (EPI == 1) {
          outf[(size_t)gr * ldc + gc] = v + bias[gc] + addend[(size_t)gr * ldadd + gc];
        } else if constexpr (EPI == 2) {
          const float z = v + bias[gc];
          outb[(size_t)gr * ldc + gc] = f2bf(z > 0.f ? z : 0.f);
        }
      }
}

// ---------------- flash attention (swapped QK^T + defer-max, __expf, reg-prefetch) ----------------
// qkv bf16 [tok][512]: q at [h*32], k at [256+h*32].  vT bf16 [b*8+h][32 d][1024 tok].
// 2048 blocks (XCD-swizzled) x 256 thr: 16 q-tiles of 64 rows x 128 bh. wave = 16 q rows.
__global__ __launch_bounds__(256) void k_attn(const unsigned short* __restrict__ qkv,
                                              const unsigned short* __restrict__ vt,
                                              unsigned short* __restrict__ attn_out) {
  __shared__ __align__(16) unsigned short Ks[64][40];
  __shared__ __align__(16) unsigned short Vs[32][72];
  __shared__ __align__(16) unsigned short Pq[4][16][72];

  const int bid  = blockIdx.x;
  const int wgid = (bid & 7) * 256 + (bid >> 3);  // bijective (2048 % 8 == 0)
  const int bh = wgid >> 4;
  const int qt = wgid & 15;
  const int b = bh >> 3, h = bh & 7;
  const int q0 = qt * 64;
  const int t = threadIdx.x, w = t >> 6, l = t & 63;
  const int lr = l & 15, hi = l >> 4, lk = hi * 8;
  const size_t base  = (size_t)b * 1024 * 512;
  const size_t vbase = (size_t)bh * 32 * 1024;
  const float sc = 0.17677669529663687f;  // 1/sqrt(32)

  const bf16x8 qf = *(const bf16x8*)&qkv[base + (size_t)(q0 + w * 16 + lr) * 512 + h * 32 + lk];

  f32x4 o0 = {0.f, 0.f, 0.f, 0.f}, o1 = {0.f, 0.f, 0.f, 0.f};
  float m = 0.f, lsum = 0.f;
  const f32x4 z4 = {0.f, 0.f, 0.f, 0.f};

  const int stok = t >> 2;         // K: token 0..63
  const int sd0  = (t & 3) * 8;    // K: 8 d elems
  const int vsd  = t >> 3;         // V: d row 0..31
  const int vtk  = (t & 7) * 8;    // V: 8 tokens

  const unsigned short* pk = &qkv[base + (size_t)stok * 512 + 256 + h * 32 + sd0];
  const unsigned short* pv = &vt[vbase + (size_t)vsd * 1024 + vtk];
  bf16x8 nk = *(const bf16x8*)pk;
  bf16x8 nv = *(const bf16x8*)pv;

  for (int kc = 0; kc < 16; kc++) {
    __syncthreads();  // previous chunk's LDS reads done
    *(bf16x8*)&Ks[stok][sd0] = nk;
    *(bf16x8*)&Vs[vsd][vtk]  = nv;
    __syncthreads();

    if (kc < 15) {  // issue next chunk's loads; latency hides under compute
      pk += 64 * 512;
      pv += 64;
      nk = *(const bf16x8*)pk;
      nv = *(const bf16x8*)pv;
    }

    // St = K @ Q^T : lane holds score(q = lr, key = blk*16 + hi*4 + r)
    f32x4 s[4];
#pragma unroll
    for (int blk = 0; blk < 4; blk++) {
      const bf16x8 kf = *(const bf16x8*)&Ks[blk * 16 + lr][lk];
      s[blk] = __builtin_amdgcn_mfma_f32_16x16x32_bf16(kf, qf, z4, 0, 0, 0);
    }

    // tree max
    const float pm = fmaxf(fmaxf(max4(s[0]), max4(s[1])), fmaxf(max4(s[2]), max4(s[3])));

    if (!__all(pm * sc <= m + 8.f)) {  // defer-max slow path (rare)
      float mx = pm;
      mx = fmaxf(mx, __shfl_xor(mx, 16));
      mx = fmaxf(mx, __shfl_xor(mx, 32));
      const float mn = fmaxf(m, mx * sc);
      const float d  = m - mn;
      lsum *= __expf(d);
#pragma unroll
      for (int r = 0; r < 4; r++) {
        const float a = __expf(__shfl(d, hi * 4 + r));
        o0[r] *= a; o1[r] *= a;
      }
      m = mn;
    }

    const float nm = -m;
    float ls = 0.f;
#pragma unroll
    for (int blk = 0; blk < 4; blk++) {
      const float p0 = __expf(fmaf(s[blk][0], sc, nm));
      const float p1 = __expf(fmaf(s[blk][1], sc, nm));
      const float p2 = __expf(fmaf(s[blk][2], sc, nm));
      const float p3 = __expf(fmaf(s[blk][3], sc, nm));
      ls += (p0 + p1) + (p2 + p3);
      ushort4 us;
      us.x = f2bf(p0); us.y = f2bf(p1); us.z = f2bf(p2); us.w = f2bf(p3);
      *(ushort4*)&Pq[w][lr][blk * 16 + hi * 4] = us;
    }
    lsum += ls;

    // O += P @ V : A = P[q][keys], B = Vs[d][keys]
#pragma unroll
    for (int ks = 0; ks < 2; ks++) {
      const bf16x8 v0f = *(const bf16x8*)&Vs[lr][ks * 32 + lk];
      const bf16x8 v1f = *(const bf16x8*)&Vs[16 + lr][ks * 32 + lk];
      const bf16x8 pa  = *(const bf16x8*)&Pq[w][lr][ks * 32 + lk];
      o0 = __builtin_amdgcn_mfma_f32_16x16x32_bf16(pa, v0f, o0, 0, 0, 0);
      o1 = __builtin_amdgcn_mfma_f32_16x16x32_bf16(pa, v1f, o1, 0, 0, 0);
    }
  }

  float lsq = lsum;
  lsq += __shfl_xor(lsq, 16);
  lsq += __shfl_xor(lsq, 32);
#pragma unroll
  for (int r = 0; r < 4; r++) {
    const int qloc = hi * 4 + r;
    const float inv = 1.f / __shfl(lsq, qloc);
    const int row = q0 + w * 16 + qloc;
    attn_out[(size_t)(b * 1024 + row) * 256 + h * 32 + lr]      = f2bf(o0[r] * inv);
    attn_out[(size_t)(b * 1024 + row) * 256 + h * 32 + 16 + lr] = f2bf(o1[r] * inv);
  }
}

// ---------------- LN2: y fp32 [tok][256] -> yln bf16 ----------------
__global__ __launch_bounds__(256) void k_ln2(const float* __restrict__ y,
                                             const float* __restrict__ g,
                                             const float* __restrict__ be,
                                             unsigned short* __restrict__ yln) {
  const int row = blockIdx.x * 4 + (threadIdx.x >> 6);
  const int l = threadIdx.x & 63;
  const float* yr = y + (size_t)row * 256;
  const float4 v = *(const float4*)(yr + l * 4);
  float s  = v.x + v.y + v.z + v.w;
  float ss = v.x * v.x + v.y * v.y + v.z * v.z + v.w * v.w;
#pragma unroll
  for (int msk = 1; msk < 64; msk <<= 1) {
    s  += __shfl_xor(s, msk);
    ss += __shfl_xor(ss, msk);
  }
  const float mean = s * (1.f / 256.f);
  const float var  = ss * (1.f / 256.f) - mean * mean;
  const float rs   = rsqrtf(var + 1e-5f);
  const float4 gv  = *(const float4*)(g + l * 4);
  const float4 bv  = *(const float4*)(be + l * 4);
  ushort4 o;
  o.x = f2bf((v.x - mean) * rs * gv.x + bv.x);
  o.y = f2bf((v.y - mean) * rs * gv.y + bv.y);
  o.z = f2bf((v.z - mean) * rs * gv.z + bv.z);
  o.w = f2bf((v.w - mean) * rs * gv.w + bv.w);
  *(ushort4*)&yln[(size_t)row * 256 + l * 4] = o;
}

// ---------------- launch ----------------
extern "C" void kernel_launch(void* const* d_in, const int* in_sizes, int n_in,
                              void* d_out, int out_size, void* d_ws, size_t ws_size,
                              hipStream_t stream) {
  const float* x      = (const float*)d_in[0];
  const float* w_qkv  = (const float*)d_in[1];
  const float* w_proj = (const float*)d_in[2];
  const float* b_proj = (const float*)d_in[3];
  const float* g1     = (const float*)d_in[4];
  const float* beta1  = (const float*)d_in[5];
  const float* g2     = (const float*)d_in[6];
  const float* beta2  = (const float*)d_in[7];
  const float* w1     = (const float*)d_in[8];
  const float* b1     = (const float*)d_in[9];
  const float* w2     = (const float*)d_in[10];
  const float* b2     = (const float*)d_in[11];
  float* out = (float*)d_out;
  char* ws = (char*)d_ws;

  constexpr size_t OFF_XT  = 0;                       // 16 MB fp32 [tok][256]
  constexpr size_t OFF_XLN = 16777216;                //  8 MB bf16
  constexpr size_t OFF_QKV = OFF_XLN + 8388608;       // 16 MB bf16 [tok][512] (Q,K only)
  constexpr size_t OFF_ATT = OFF_QKV + 16777216;      //  8 MB bf16
  constexpr size_t OFF_Y   = OFF_ATT + 8388608;       // 16 MB fp32 (aliases vT before GEMM<1>)
  constexpr size_t OFF_YLN = OFF_Y + 16777216;        //  8 MB bf16
  constexpr size_t OFF_W   = OFF_YLN + 8388608;       // weights bf16
  constexpr size_t OFF_H1  = OFF_XLN;                 // alias: 32 MB bf16 [tok][1024]
  constexpr size_t OFF_VT  = OFF_Y;                   // alias: 8 MB bf16 [bh][32][1024]

  float*          xt    = (float*)(ws + OFF_XT);
  unsigned short* xln   = (unsigned short*)(ws + OFF_XLN);
  unsigned short* qkv   = (unsigned short*)(ws + OFF_QKV);
  unsigned short* attn  = (unsigned short*)(ws + OFF_ATT);
  float*          y     = (float*)(ws + OFF_Y);
  unsigned short* yln   = (unsigned short*)(ws + OFF_YLN);
  unsigned short* h1    = (unsigned short*)(ws + OFF_H1);
  unsigned short* vtb   = (unsigned short*)(ws + OFF_VT);
  unsigned short* wqkvb = (unsigned short*)(ws + OFF_W);
  unsigned short* wprjb = (unsigned short*)(ws + OFF_W + 393216);
  unsigned short* w1b   = (unsigned short*)(ws + OFF_W + 393216 + 131072);
  unsigned short* w2b   = (unsigned short*)(ws + OFF_W + 393216 + 131072 + 524288);

  k_casts<<<768, 256, 0, stream>>>(w_qkv, w_proj, w1, w2, wqkvb, wprjb, w1b, w2b);

  k_ln1<<<dim3(32, 16), 256, 0, stream>>>(x, g1, beta1, xt, xln);

  // qkv = xln @ w_qkv^T : Q,K -> qkv[tok][512]; V -> vT[bh][d][tok]
  k_gemm<0, 6, 128><<<768, 256, 0, stream>>>(xln, 256, wqkvb, 256, 256,
                                             nullptr, nullptr, 0, nullptr, qkv, 512, vtb);

  k_attn<<<2048, 256, 0, stream>>>(qkv, vtb, attn);

  // y = attn @ w_proj^T + b_proj + xt
  k_gemm<1, 2, 64><<<512, 256, 0, stream>>>(attn, 256, wprjb, 256, 256,
                                            b_proj, xt, 256, y, nullptr, 256, nullptr);

  k_ln2<<<4096, 256, 0, stream>>>(y, g2, beta2, yln);

  // h1 = relu(yln @ w1^T + b1)
  k_gemm<2, 8, 128><<<1024, 256, 0, stream>>>(yln, 256, w1b, 256, 256,
                                              b1, nullptr, 0, nullptr, h1, 1024, nullptr);

  // out = transpose(h1 @ w2^T + b2 + y)  (direct [b][c][s] write)
  k_gemm<3, 2, 64><<<512, 256, 0, stream>>>(h1, 1024, w2b, 1024, 1024,
                                            b2, y, 256, out, nullptr, 256, nullptr);
}

// Round 7
// 135.691 us; speedup vs baseline: 1.3845x; 1.0516x over previous
//
#include <hip/hip_runtime.h>
#include <hip/hip_bf16.h>

typedef __attribute__((ext_vector_type(8))) short bf16x8;
typedef __attribute__((ext_vector_type(4))) float f32x4;

#define DEVI __device__ __forceinline__

DEVI unsigned short f2bf(float f) {
  __hip_bfloat16 h = __float2bfloat16(f);
  return *reinterpret_cast<unsigned short*>(&h);
}

DEVI float bf2f(unsigned short u) {
  union { unsigned u; float f; } v; v.u = ((unsigned)u) << 16; return v.f;
}

DEVI unsigned cvtpk(float lo, float hi) {
  unsigned r;
  asm("v_cvt_pk_bf16_f32 %0, %1, %2" : "=v"(r) : "v"(lo), "v"(hi));
  return r;
}

DEVI void gload16(const void* g, void* l) {
  __builtin_amdgcn_global_load_lds((const __attribute__((address_space(1))) void*)g,
                                   (__attribute__((address_space(3))) void*)l, 16, 0, 0);
}

DEVI float max4(const f32x4 v) {
  return fmaxf(fmaxf(v[0], v[1]), fmaxf(v[2], v[3]));
}

// ---------------- fused weight casts fp32 -> bf16 (float4 vectorized) ----------------
__global__ __launch_bounds__(256) void k_casts(const float* __restrict__ a, const float* __restrict__ b,
                                               const float* __restrict__ c, const float* __restrict__ d,
                                               unsigned short* __restrict__ oa, unsigned short* __restrict__ ob,
                                               unsigned short* __restrict__ oc, unsigned short* __restrict__ od) {
  const int i4 = (blockIdx.x * 256 + threadIdx.x) * 4;
  const float* src; unsigned short* dst; int off;
  if (i4 < 196608)      { src = a; dst = oa; off = 0; }
  else if (i4 < 262144) { src = b; dst = ob; off = 196608; }
  else if (i4 < 524288) { src = c; dst = oc; off = 262144; }
  else                  { src = d; dst = od; off = 524288; }
  const int j = i4 - off;
  const float4 v = *(const float4*)(src + j);
  ushort4 o;
  o.x = f2bf(v.x); o.y = f2bf(v.y); o.z = f2bf(v.z); o.w = f2bf(v.w);
  *(ushort4*)(dst + j) = o;
}

// ---------------- LN1 + transpose: x[b][c][p] -> xt bf16 [tok][c], xln bf16 [tok][c] ----------------
__global__ __launch_bounds__(256) void k_ln1(const float* __restrict__ x,
                                             const float* __restrict__ g,
                                             const float* __restrict__ be,
                                             unsigned short* __restrict__ xt,
                                             unsigned short* __restrict__ xln) {
  __shared__ float tile[256][33];
  const int b  = blockIdx.y;
  const int p0 = blockIdx.x * 32;
  const int t  = threadIdx.x;
  const float* src = x + ((size_t)b * 256 + t) * 1024 + p0;
#pragma unroll
  for (int j = 0; j < 32; j += 4) {
    float4 v = *(const float4*)(src + j);
    tile[t][j] = v.x; tile[t][j + 1] = v.y; tile[t][j + 2] = v.z; tile[t][j + 3] = v.w;
  }
  __syncthreads();
  const int w = t >> 6, l = t & 63;
#pragma unroll
  for (int i = 0; i < 8; i++) {
    const int p = w * 8 + i;
    float s = 0.f, ss = 0.f;
#pragma unroll
    for (int q = 0; q < 4; q++) {
      float v = tile[l + 64 * q][p];
      s += v; ss += v * v;
    }
#pragma unroll
    for (int msk = 1; msk < 64; msk <<= 1) {
      s  += __shfl_xor(s, msk);
      ss += __shfl_xor(ss, msk);
    }
    const float mean = s * (1.f / 256.f);
    const float var  = ss * (1.f / 256.f) - mean * mean;
    const float rs   = rsqrtf(var + 1e-5f);
    const size_t token = (size_t)b * 1024 + p0 + p;
#pragma unroll
    for (int q = 0; q < 4; q++) {
      const int c = l + 64 * q;
      const float v = tile[c][p];
      xt[token * 256 + c]  = f2bf(v);
      xln[token * 256 + c] = f2bf((v - mean) * rs * g[c] + be[c]);
    }
  }
}

// ---------------- GEMM: C[M,N] = A[M,K] @ B[N,K]^T, bf16 in, fp32 acc ----------------
// Double-buffered LDS, 1 barrier per k-step. BM in {64,128}, BN=128.
// EPI 0: store bf16 (qkv); n0>=512 (V cols): swapped MFMA -> vT[bh][d][tok]
// EPI 1: +bias +bf16 addend -> bf16 (proj + residual)
// EPI 2: +bias, relu -> bf16 (ffn1)
// EPI 3: swapped MFMA; +bias +bf16 addend(y[tok][c]) -> out[b][c][s] fp32 (folds k_tout)
template <int EPI, int NN, int BM>
__global__ __launch_bounds__(256) void k_gemm(const unsigned short* __restrict__ A, int lda,
                                              const unsigned short* __restrict__ Bw, int ldb,
                                              int K,
                                              const float* __restrict__ bias,
                                              const unsigned short* __restrict__ addend, int ldadd,
                                              float* __restrict__ outf,
                                              unsigned short* __restrict__ outb, int ldc,
                                              unsigned short* __restrict__ vtb) {
  constexpr int MI = BM / 32;
  constexpr int IA = (BM * 64) / 2048;
  __shared__ __align__(16) unsigned short As[2][BM * 64];
  __shared__ __align__(16) unsigned short Bs[2][128 * 64];
  const int nwg = gridDim.x;
  const int id  = (blockIdx.x & 7) * (nwg >> 3) + (blockIdx.x >> 3);
  const int m0  = (id / NN) * BM, n0 = (id % NN) * 128;
  const int t  = threadIdx.x;
  const int w  = t >> 6, l = t & 63;
  const int wm = (w >> 1) * (BM / 2), wn = (w & 1) * 64;
  const int lr = l & 15, hi = l >> 4, lk = hi * 8;
  const bool swp = (EPI == 3) || ((EPI == 0) && (n0 >= 512));
  f32x4 acc[MI][4] = {};
  const int nkt = K >> 6;
  const int e  = t * 8;
  const int er = e >> 6, ec = e & 63;

#pragma unroll
  for (int i = 0; i < IA; i++)
    gload16(&A[(size_t)(m0 + er + i * 32) * lda + ec], &As[0][e + i * 2048]);
#pragma unroll
  for (int i = 0; i < 4; i++)
    gload16(&Bw[(size_t)(n0 + er + i * 32) * ldb + ec], &Bs[0][e + i * 2048]);

  for (int kt = 0; kt < nkt; ++kt) {
    const int cur = kt & 1;
    __syncthreads();
    if (kt + 1 < nkt) {
      const int kn = (kt + 1) * 64;
#pragma unroll
      for (int i = 0; i < IA; i++)
        gload16(&A[(size_t)(m0 + er + i * 32) * lda + kn + ec], &As[cur ^ 1][e + i * 2048]);
#pragma unroll
      for (int i = 0; i < 4; i++)
        gload16(&Bw[(size_t)(n0 + er + i * 32) * ldb + kn + ec], &Bs[cur ^ 1][e + i * 2048]);
    }
#pragma unroll
    for (int ks = 0; ks < 2; ks++) {
      bf16x8 af[MI], bfr[4];
#pragma unroll
      for (int i = 0; i < MI; i++) af[i] = *(const bf16x8*)&As[cur][(wm + i * 16 + lr) * 64 + ks * 32 + lk];
#pragma unroll
      for (int j = 0; j < 4; j++) bfr[j] = *(const bf16x8*)&Bs[cur][(wn + j * 16 + lr) * 64 + ks * 32 + lk];
      if (swp) {
#pragma unroll
        for (int i = 0; i < MI; i++)
#pragma unroll
          for (int j = 0; j < 4; j++)
            acc[i][j] = __builtin_amdgcn_mfma_f32_16x16x32_bf16(bfr[j], af[i], acc[i][j], 0, 0, 0);
      } else {
#pragma unroll
        for (int i = 0; i < MI; i++)
#pragma unroll
          for (int j = 0; j < 4; j++)
            acc[i][j] = __builtin_amdgcn_mfma_f32_16x16x32_bf16(af[i], bfr[j], acc[i][j], 0, 0, 0);
      }
    }
  }

  if constexpr (EPI == 3) {
#pragma unroll
    for (int i = 0; i < MI; i++)
#pragma unroll
      for (int j = 0; j < 4; j++)
#pragma unroll
        for (int r = 0; r < 4; r++) {
          const int c  = n0 + wn + j * 16 + hi * 4 + r;
          const int gm = m0 + wm + i * 16 + lr;
          const int b  = gm >> 10, sI = gm & 1023;
          outf[((size_t)b * 256 + c) * 1024 + sI] =
              acc[i][j][r] + bias[c] + bf2f(addend[(size_t)gm * 256 + c]);
        }
    return;
  }
  if ((EPI == 0) && (n0 >= 512)) {
#pragma unroll
    for (int i = 0; i < MI; i++)
#pragma unroll
      for (int j = 0; j < 4; j++)
#pragma unroll
        for (int r = 0; r < 4; r++) {
          const int gn = n0 + wn + j * 16 + hi * 4 + r;
          const int gm = m0 + wm + i * 16 + lr;
          const int c = gn - 512;
          const int b = gm >> 10;
          vtb[(size_t)(b * 256 + c) * 1024 + (gm & 1023)] = f2bf(acc[i][j][r]);
        }
    return;
  }
#pragma unroll
  for (int i = 0; i < MI; i++)
#pragma unroll
    for (int j = 0; j < 4; j++)
#pragma unroll
      for (int r = 0; r < 4; r++) {
        const int gr = m0 + wm + i * 16 + hi * 4 + r;
        const int gc = n0 + wn + j * 16 + lr;
        const float v = acc[i][j][r];
        if constexpr (EPI == 0) {
          outb[(size_t)gr * ldc + gc] = f2bf(v);
        } else if constexpr (EPI == 1) {
          outb[(size_t)gr * ldc + gc] = f2bf(v + bias[gc] + bf2f(addend[(size_t)gr * ldadd + gc]));
        } else if constexpr (EPI == 2) {
          const float z = v + bias[gc];
          outb[(size_t)gr * ldc + gc] = f2bf(z > 0.f ? z : 0.f);
        }
      }
}

// ---------------- flash attention: P fully in-register via permuted K staging ----------------
// qkv bf16 [tok][512]: q at [h*32], k at [256+h*32].  vT bf16 [b*8+h][32 d][1024 tok].
// K rows staged at permuted row rho(k) so QK^T output lands lane-group hi <- keys hi*8..+7:
// the PV A-fragment layout. P: 16 exp -> 8 cvt_pk -> MFMA. No P LDS round-trip.
__global__ __launch_bounds__(256) void k_attn(const unsigned short* __restrict__ qkv,
                                              const unsigned short* __restrict__ vt,
                                              unsigned short* __restrict__ attn_out) {
  __shared__ __align__(16) unsigned short Ks[64][40];
  __shared__ __align__(16) unsigned short Vs[32][72];

  const int bid  = blockIdx.x;
  const int wgid = (bid & 7) * 256 + (bid >> 3);  // bijective (2048 % 8 == 0)
  const int bh = wgid >> 4;
  const int qt = wgid & 15;
  const int b = bh >> 3, h = bh & 7;
  const int q0 = qt * 64;
  const int t = threadIdx.x, w = t >> 6, l = t & 63;
  const int lr = l & 15, hi = l >> 4, lk = hi * 8;
  const size_t base  = (size_t)b * 1024 * 512;
  const size_t vbase = (size_t)bh * 32 * 1024;
  const float sc = 0.17677669529663687f;  // 1/sqrt(32)

  const bf16x8 qf = *(const bf16x8*)&qkv[base + (size_t)(q0 + w * 16 + lr) * 512 + h * 32 + lk];

  f32x4 o0 = {0.f, 0.f, 0.f, 0.f}, o1 = {0.f, 0.f, 0.f, 0.f};
  float m = 0.f, lsum = 0.f;
  const f32x4 z4 = {0.f, 0.f, 0.f, 0.f};

  const int stok = t >> 2;         // K: token 0..63
  const int sd0  = (t & 3) * 8;    // K: 8 d elems
  // permuted K row: key k -> row ((k>>2)&1)*16 + ((k>>3)&3)*4 + (k&3) + (k&32)
  const int prow = ((stok >> 2) & 1) * 16 + ((stok >> 3) & 3) * 4 + (stok & 3) + (stok & 32);
  const int vsd  = t >> 3;         // V: d row 0..31
  const int vtk  = (t & 7) * 8;    // V: 8 tokens

  const unsigned short* pk = &qkv[base + (size_t)stok * 512 + 256 + h * 32 + sd0];
  const unsigned short* pv = &vt[vbase + (size_t)vsd * 1024 + vtk];
  bf16x8 nk = *(const bf16x8*)pk;
  bf16x8 nv = *(const bf16x8*)pv;

  for (int kc = 0; kc < 16; kc++) {
    __syncthreads();
    *(bf16x8*)&Ks[prow][sd0] = nk;
    *(bf16x8*)&Vs[vsd][vtk]  = nv;
    __syncthreads();

    if (kc < 15) {
      pk += 64 * 512;
      pv += 64;
      nk = *(const bf16x8*)pk;
      nv = *(const bf16x8*)pv;
    }

    // St = K_perm @ Q^T : lane (lr,hi) gets s[blk][r] = score(q=lr, key = hi*8+(blk&1)*4+r+(blk>>1)*32)
    f32x4 s[4];
    __builtin_amdgcn_s_setprio(1);
#pragma unroll
    for (int blk = 0; blk < 4; blk++) {
      const bf16x8 kf = *(const bf16x8*)&Ks[blk * 16 + lr][lk];
      s[blk] = __builtin_amdgcn_mfma_f32_16x16x32_bf16(kf, qf, z4, 0, 0, 0);
    }
    __builtin_amdgcn_s_setprio(0);

    const float pm = fmaxf(fmaxf(max4(s[0]), max4(s[1])), fmaxf(max4(s[2]), max4(s[3])));

    if (!__all(pm * sc <= m + 8.f)) {  // defer-max slow path (rare)
      float mx = pm;
      mx = fmaxf(mx, __shfl_xor(mx, 16));
      mx = fmaxf(mx, __shfl_xor(mx, 32));
      const float mn = fmaxf(m, mx * sc);
      const float d  = m - mn;
      lsum *= __expf(d);
#pragma unroll
      for (int r = 0; r < 4; r++) {
        const float a = __expf(__shfl(d, hi * 4 + r));
        o0[r] *= a; o1[r] *= a;
      }
      m = mn;
    }

    const float nm = -m;
    unsigned pu[8];
    float ls = 0.f;
#pragma unroll
    for (int blk = 0; blk < 4; blk++) {
      const float p0 = __expf(fmaf(s[blk][0], sc, nm));
      const float p1 = __expf(fmaf(s[blk][1], sc, nm));
      const float p2 = __expf(fmaf(s[blk][2], sc, nm));
      const float p3 = __expf(fmaf(s[blk][3], sc, nm));
      ls += (p0 + p1) + (p2 + p3);
      pu[blk * 2]     = cvtpk(p0, p1);
      pu[blk * 2 + 1] = cvtpk(p2, p3);
    }
    lsum += ls;

    union U { unsigned u[4]; bf16x8 v; };
    U a0, a1;
    a0.u[0] = pu[0]; a0.u[1] = pu[1]; a0.u[2] = pu[2]; a0.u[3] = pu[3];
    a1.u[0] = pu[4]; a1.u[1] = pu[5]; a1.u[2] = pu[6]; a1.u[3] = pu[7];

    // O += P @ V : A = P (in-register), B = Vs[d][keys]
    __builtin_amdgcn_s_setprio(1);
#pragma unroll
    for (int ks = 0; ks < 2; ks++) {
      const bf16x8 pa  = (ks == 0) ? a0.v : a1.v;
      const bf16x8 v0f = *(const bf16x8*)&Vs[lr][ks * 32 + lk];
      const bf16x8 v1f = *(const bf16x8*)&Vs[16 + lr][ks * 32 + lk];
      o0 = __builtin_amdgcn_mfma_f32_16x16x32_bf16(pa, v0f, o0, 0, 0, 0);
      o1 = __builtin_amdgcn_mfma_f32_16x16x32_bf16(pa, v1f, o1, 0, 0, 0);
    }
    __builtin_amdgcn_s_setprio(0);
  }

  float lsq = lsum;
  lsq += __shfl_xor(lsq, 16);
  lsq += __shfl_xor(lsq, 32);
#pragma unroll
  for (int r = 0; r < 4; r++) {
    const int qloc = hi * 4 + r;
    const float inv = 1.f / __shfl(lsq, qloc);
    const int row = q0 + w * 16 + qloc;
    attn_out[(size_t)(b * 1024 + row) * 256 + h * 32 + lr]      = f2bf(o0[r] * inv);
    attn_out[(size_t)(b * 1024 + row) * 256 + h * 32 + 16 + lr] = f2bf(o1[r] * inv);
  }
}

// ---------------- LN2: y bf16 [tok][256] -> yln bf16 ----------------
__global__ __launch_bounds__(256) void k_ln2(const unsigned short* __restrict__ y,
                                             const float* __restrict__ g,
                                             const float* __restrict__ be,
                                             unsigned short* __restrict__ yln) {
  const int row = blockIdx.x * 4 + (threadIdx.x >> 6);
  const int l = threadIdx.x & 63;
  const unsigned short* yr = y + (size_t)row * 256;
  const ushort4 u = *(const ushort4*)(yr + l * 4);
  const float v0 = bf2f(u.x), v1 = bf2f(u.y), v2 = bf2f(u.z), v3 = bf2f(u.w);
  float s  = v0 + v1 + v2 + v3;
  float ss = v0 * v0 + v1 * v1 + v2 * v2 + v3 * v3;
#pragma unroll
  for (int msk = 1; msk < 64; msk <<= 1) {
    s  += __shfl_xor(s, msk);
    ss += __shfl_xor(ss, msk);
  }
  const float mean = s * (1.f / 256.f);
  const float var  = ss * (1.f / 256.f) - mean * mean;
  const float rs   = rsqrtf(var + 1e-5f);
  const float4 gv  = *(const float4*)(g + l * 4);
  const float4 bv  = *(const float4*)(be + l * 4);
  ushort4 o;
  o.x = f2bf((v0 - mean) * rs * gv.x + bv.x);
  o.y = f2bf((v1 - mean) * rs * gv.y + bv.y);
  o.z = f2bf((v2 - mean) * rs * gv.z + bv.z);
  o.w = f2bf((v3 - mean) * rs * gv.w + bv.w);
  *(ushort4*)&yln[(size_t)row * 256 + l * 4] = o;
}

// ---------------- launch ----------------
extern "C" void kernel_launch(void* const* d_in, const int* in_sizes, int n_in,
                              void* d_out, int out_size, void* d_ws, size_t ws_size,
                              hipStream_t stream) {
  const float* x      = (const float*)d_in[0];
  const float* w_qkv  = (const float*)d_in[1];
  const float* w_proj = (const float*)d_in[2];
  const float* b_proj = (const float*)d_in[3];
  const float* g1     = (const float*)d_in[4];
  const float* beta1  = (const float*)d_in[5];
  const float* g2     = (const float*)d_in[6];
  const float* beta2  = (const float*)d_in[7];
  const float* w1     = (const float*)d_in[8];
  const float* b1     = (const float*)d_in[9];
  const float* w2     = (const float*)d_in[10];
  const float* b2     = (const float*)d_in[11];
  float* out = (float*)d_out;
  char* ws = (char*)d_ws;

  constexpr size_t OFF_XT  = 0;                       //  8 MB bf16 [tok][256]
  constexpr size_t OFF_XLN = 16777216;                //  8 MB bf16
  constexpr size_t OFF_QKV = OFF_XLN + 8388608;       // 16 MB bf16 [tok][512] (Q,K only)
  constexpr size_t OFF_ATT = OFF_QKV + 16777216;      //  8 MB bf16
  constexpr size_t OFF_Y   = OFF_ATT + 8388608;       //  8 MB bf16 (aliases vT before GEMM<1>)
  constexpr size_t OFF_YLN = OFF_Y + 16777216;        //  8 MB bf16
  constexpr size_t OFF_W   = OFF_YLN + 8388608;       // weights bf16
  constexpr size_t OFF_H1  = OFF_XLN;                 // alias: 32 MB bf16 [tok][1024]
  constexpr size_t OFF_VT  = OFF_Y;                   // alias: 8 MB bf16 [bh][32][1024]

  unsigned short* xt    = (unsigned short*)(ws + OFF_XT);
  unsigned short* xln   = (unsigned short*)(ws + OFF_XLN);
  unsigned short* qkv   = (unsigned short*)(ws + OFF_QKV);
  unsigned short* attn  = (unsigned short*)(ws + OFF_ATT);
  unsigned short* y     = (unsigned short*)(ws + OFF_Y);
  unsigned short* yln   = (unsigned short*)(ws + OFF_YLN);
  unsigned short* h1    = (unsigned short*)(ws + OFF_H1);
  unsigned short* vtb   = (unsigned short*)(ws + OFF_VT);
  unsigned short* wqkvb = (unsigned short*)(ws + OFF_W);
  unsigned short* wprjb = (unsigned short*)(ws + OFF_W + 393216);
  unsigned short* w1b   = (unsigned short*)(ws + OFF_W + 393216 + 131072);
  unsigned short* w2b   = (unsigned short*)(ws + OFF_W + 393216 + 131072 + 524288);

  k_casts<<<768, 256, 0, stream>>>(w_qkv, w_proj, w1, w2, wqkvb, wprjb, w1b, w2b);

  k_ln1<<<dim3(32, 16), 256, 0, stream>>>(x, g1, beta1, xt, xln);

  // qkv = xln @ w_qkv^T : Q,K -> qkv[tok][512]; V -> vT[bh][d][tok]
  k_gemm<0, 6, 128><<<768, 256, 0, stream>>>(xln, 256, wqkvb, 256, 256,
                                             nullptr, nullptr, 0, nullptr, qkv, 512, vtb);

  k_attn<<<2048, 256, 0, stream>>>(qkv, vtb, attn);

  // y = attn @ w_proj^T + b_proj + xt  (bf16)
  k_gemm<1, 2, 64><<<512, 256, 0, stream>>>(attn, 256, wprjb, 256, 256,
                                            b_proj, xt, 256, nullptr, y, 256, nullptr);

  k_ln2<<<4096, 256, 0, stream>>>(y, g2, beta2, yln);

  // h1 = relu(yln @ w1^T + b1)
  k_gemm<2, 8, 128><<<1024, 256, 0, stream>>>(yln, 256, w1b, 256, 256,
                                              b1, nullptr, 0, nullptr, h1, 1024, nullptr);

  // out = transpose(h1 @ w2^T + b2 + y)  (direct [b][c][s] write)
  k_gemm<3, 2, 64><<<512, 256, 0, stream>>>(h1, 1024, w2b, 1024, 1024,
                                            b2, y, 256, out, nullptr, 256, nullptr);
}

// Round 8
// 129.167 us; speedup vs baseline: 1.4544x; 1.0505x over previous
//
#include <hip/hip_runtime.h>
#include <hip/hip_bf16.h>

typedef __attribute__((ext_vector_type(8))) short bf16x8;
typedef __attribute__((ext_vector_type(4))) float f32x4;

#define DEVI __device__ __forceinline__

// exp dispatch: raw v_exp (exp2) when builtin exists, else fast-libm expf.
// QSCALE applied to Q in the qkv-GEMM epilogue puts scores directly in exp's domain.
#if __has_builtin(__builtin_amdgcn_exp2f)
#define EXPX(x) __builtin_amdgcn_exp2f(x)
#define QSCALE 0.2550348744f        /* (1/sqrt(32)) * log2(e) */
#define THR 11.541560327f           /* 8 * log2(e) */
#else
#define EXPX(x) __expf(x)
#define QSCALE 0.17677669529663687f /* 1/sqrt(32) */
#define THR 8.f
#endif

DEVI unsigned short f2bf(float f) {
  __hip_bfloat16 h = __float2bfloat16(f);
  return *reinterpret_cast<unsigned short*>(&h);
}

DEVI float bf2f(unsigned short u) {
  union { unsigned u; float f; } v; v.u = ((unsigned)u) << 16; return v.f;
}

DEVI unsigned cvtpk(float lo, float hi) {
  unsigned r;
  asm("v_cvt_pk_bf16_f32 %0, %1, %2" : "=v"(r) : "v"(lo), "v"(hi));
  return r;
}

DEVI void gload16(const void* g, void* l) {
  __builtin_amdgcn_global_load_lds((const __attribute__((address_space(1))) void*)g,
                                   (__attribute__((address_space(3))) void*)l, 16, 0, 0);
}

DEVI float max3f(float a, float b, float c) { return fmaxf(fmaxf(a, b), c); }

// ---------------- fused weight casts fp32 -> bf16 (float4 vectorized) ----------------
__global__ __launch_bounds__(256) void k_casts(const float* __restrict__ a, const float* __restrict__ b,
                                               const float* __restrict__ c, const float* __restrict__ d,
                                               unsigned short* __restrict__ oa, unsigned short* __restrict__ ob,
                                               unsigned short* __restrict__ oc, unsigned short* __restrict__ od) {
  const int i4 = (blockIdx.x * 256 + threadIdx.x) * 4;
  const float* src; unsigned short* dst; int off;
  if (i4 < 196608)      { src = a; dst = oa; off = 0; }
  else if (i4 < 262144) { src = b; dst = ob; off = 196608; }
  else if (i4 < 524288) { src = c; dst = oc; off = 262144; }
  else                  { src = d; dst = od; off = 524288; }
  const int j = i4 - off;
  const float4 v = *(const float4*)(src + j);
  ushort4 o;
  o.x = f2bf(v.x); o.y = f2bf(v.y); o.z = f2bf(v.z); o.w = f2bf(v.w);
  *(ushort4*)(dst + j) = o;
}

// ---------------- LN1 + transpose: x[b][c][p] -> xt bf16 [tok][c], xln bf16 [tok][c] ----------------
__global__ __launch_bounds__(256) void k_ln1(const float* __restrict__ x,
                                             const float* __restrict__ g,
                                             const float* __restrict__ be,
                                             unsigned short* __restrict__ xt,
                                             unsigned short* __restrict__ xln) {
  __shared__ float tile[256][33];
  const int b  = blockIdx.y;
  const int p0 = blockIdx.x * 32;
  const int t  = threadIdx.x;
  const float* src = x + ((size_t)b * 256 + t) * 1024 + p0;
#pragma unroll
  for (int j = 0; j < 32; j += 4) {
    float4 v = *(const float4*)(src + j);
    tile[t][j] = v.x; tile[t][j + 1] = v.y; tile[t][j + 2] = v.z; tile[t][j + 3] = v.w;
  }
  __syncthreads();
  const int w = t >> 6, l = t & 63;
#pragma unroll
  for (int i = 0; i < 8; i++) {
    const int p = w * 8 + i;
    float s = 0.f, ss = 0.f;
#pragma unroll
    for (int q = 0; q < 4; q++) {
      float v = tile[l + 64 * q][p];
      s += v; ss += v * v;
    }
#pragma unroll
    for (int msk = 1; msk < 64; msk <<= 1) {
      s  += __shfl_xor(s, msk);
      ss += __shfl_xor(ss, msk);
    }
    const float mean = s * (1.f / 256.f);
    const float var  = ss * (1.f / 256.f) - mean * mean;
    const float rs   = rsqrtf(var + 1e-5f);
    const size_t token = (size_t)b * 1024 + p0 + p;
#pragma unroll
    for (int q = 0; q < 4; q++) {
      const int c = l + 64 * q;
      const float v = tile[c][p];
      xt[token * 256 + c]  = f2bf(v);
      xln[token * 256 + c] = f2bf((v - mean) * rs * g[c] + be[c]);
    }
  }
}

// ---------------- GEMM: C[M,N] = A[M,K] @ B[N,K]^T, bf16 in, fp32 acc ----------------
// Double-buffered LDS, 1 barrier per k-step. BM in {64,128}, BN=128.
// EPI 0: store bf16 (qkv); Q cols (n0<256) pre-scaled by QSCALE; n0>=512 (V): swapped MFMA -> vT
// EPI 1: +bias +bf16 addend -> bf16 (proj + residual)
// EPI 2: +bias, relu -> bf16 (ffn1)
// EPI 3: swapped MFMA; +bias +bf16 addend -> out[b][c][s] fp32 (folds k_tout)
template <int EPI, int NN, int BM>
__global__ __launch_bounds__(256) void k_gemm(const unsigned short* __restrict__ A, int lda,
                                              const unsigned short* __restrict__ Bw, int ldb,
                                              int K,
                                              const float* __restrict__ bias,
                                              const unsigned short* __restrict__ addend, int ldadd,
                                              float* __restrict__ outf,
                                              unsigned short* __restrict__ outb, int ldc,
                                              unsigned short* __restrict__ vtb) {
  constexpr int MI = BM / 32;
  constexpr int IA = (BM * 64) / 2048;
  __shared__ __align__(16) unsigned short As[2][BM * 64];
  __shared__ __align__(16) unsigned short Bs[2][128 * 64];
  const int nwg = gridDim.x;
  const int id  = (blockIdx.x & 7) * (nwg >> 3) + (blockIdx.x >> 3);
  const int m0  = (id / NN) * BM, n0 = (id % NN) * 128;
  const int t  = threadIdx.x;
  const int w  = t >> 6, l = t & 63;
  const int wm = (w >> 1) * (BM / 2), wn = (w & 1) * 64;
  const int lr = l & 15, hi = l >> 4, lk = hi * 8;
  const bool swp = (EPI == 3) || ((EPI == 0) && (n0 >= 512));
  const float qs = ((EPI == 0) && (n0 < 256)) ? QSCALE : 1.f;
  f32x4 acc[MI][4] = {};
  const int nkt = K >> 6;
  const int e  = t * 8;
  const int er = e >> 6, ec = e & 63;

#pragma unroll
  for (int i = 0; i < IA; i++)
    gload16(&A[(size_t)(m0 + er + i * 32) * lda + ec], &As[0][e + i * 2048]);
#pragma unroll
  for (int i = 0; i < 4; i++)
    gload16(&Bw[(size_t)(n0 + er + i * 32) * ldb + ec], &Bs[0][e + i * 2048]);

  for (int kt = 0; kt < nkt; ++kt) {
    const int cur = kt & 1;
    __syncthreads();
    if (kt + 1 < nkt) {
      const int kn = (kt + 1) * 64;
#pragma unroll
      for (int i = 0; i < IA; i++)
        gload16(&A[(size_t)(m0 + er + i * 32) * lda + kn + ec], &As[cur ^ 1][e + i * 2048]);
#pragma unroll
      for (int i = 0; i < 4; i++)
        gload16(&Bw[(size_t)(n0 + er + i * 32) * ldb + kn + ec], &Bs[cur ^ 1][e + i * 2048]);
    }
#pragma unroll
    for (int ks = 0; ks < 2; ks++) {
      bf16x8 af[MI], bfr[4];
#pragma unroll
      for (int i = 0; i < MI; i++) af[i] = *(const bf16x8*)&As[cur][(wm + i * 16 + lr) * 64 + ks * 32 + lk];
#pragma unroll
      for (int j = 0; j < 4; j++) bfr[j] = *(const bf16x8*)&Bs[cur][(wn + j * 16 + lr) * 64 + ks * 32 + lk];
      if (swp) {
#pragma unroll
        for (int i = 0; i < MI; i++)
#pragma unroll
          for (int j = 0; j < 4; j++)
            acc[i][j] = __builtin_amdgcn_mfma_f32_16x16x32_bf16(bfr[j], af[i], acc[i][j], 0, 0, 0);
      } else {
#pragma unroll
        for (int i = 0; i < MI; i++)
#pragma unroll
          for (int j = 0; j < 4; j++)
            acc[i][j] = __builtin_amdgcn_mfma_f32_16x16x32_bf16(af[i], bfr[j], acc[i][j], 0, 0, 0);
      }
    }
  }

  if constexpr (EPI == 3) {
#pragma unroll
    for (int i = 0; i < MI; i++)
#pragma unroll
      for (int j = 0; j < 4; j++)
#pragma unroll
        for (int r = 0; r < 4; r++) {
          const int c  = n0 + wn + j * 16 + hi * 4 + r;
          const int gm = m0 + wm + i * 16 + lr;
          const int b  = gm >> 10, sI = gm & 1023;
          outf[((size_t)b * 256 + c) * 1024 + sI] =
              acc[i][j][r] + bias[c] + bf2f(addend[(size_t)gm * 256 + c]);
        }
    return;
  }
  if ((EPI == 0) && (n0 >= 512)) {
#pragma unroll
    for (int i = 0; i < MI; i++)
#pragma unroll
      for (int j = 0; j < 4; j++)
#pragma unroll
        for (int r = 0; r < 4; r++) {
          const int gn = n0 + wn + j * 16 + hi * 4 + r;
          const int gm = m0 + wm + i * 16 + lr;
          const int c = gn - 512;
          const int b = gm >> 10;
          vtb[(size_t)(b * 256 + c) * 1024 + (gm & 1023)] = f2bf(acc[i][j][r]);
        }
    return;
  }
#pragma unroll
  for (int i = 0; i < MI; i++)
#pragma unroll
    for (int j = 0; j < 4; j++)
#pragma unroll
      for (int r = 0; r < 4; r++) {
        const int gr = m0 + wm + i * 16 + hi * 4 + r;
        const int gc = n0 + wn + j * 16 + lr;
        const float v = acc[i][j][r];
        if constexpr (EPI == 0) {
          outb[(size_t)gr * ldc + gc] = f2bf(v * qs);
        } else if constexpr (EPI == 1) {
          outb[(size_t)gr * ldc + gc] = f2bf(v + bias[gc] + bf2f(addend[(size_t)gr * ldadd + gc]));
        } else if constexpr (EPI == 2) {
          const float z = v + bias[gc];
          outb[(size_t)gr * ldc + gc] = f2bf(z > 0.f ? z : 0.f);
        }
      }
}

// ---------------- flash attention: in-reg P, C-folded max, MFMA row-sum ----------------
// qkv bf16 [tok][512]: q (pre-scaled by QSCALE) at [h*32], k at [256+h*32].
// vT bf16 [b*8+h][32 d][1024 tok].  Permuted K staging (QK^T out == PV A-frag layout).
// QK MFMA's C-operand carries -m so scores arrive max-subtracted; row-sum via ones-MFMA.
__global__ __launch_bounds__(256) void k_attn(const unsigned short* __restrict__ qkv,
                                              const unsigned short* __restrict__ vt,
                                              unsigned short* __restrict__ attn_out) {
  __shared__ __align__(16) unsigned short Ks[64][40];
  __shared__ __align__(16) unsigned short Vs[32][72];

  const int bid  = blockIdx.x;
  const int wgid = (bid & 7) * 256 + (bid >> 3);  // bijective (2048 % 8 == 0)
  const int bh = wgid >> 4;
  const int qt = wgid & 15;
  const int b = bh >> 3, h = bh & 7;
  const int q0 = qt * 64;
  const int t = threadIdx.x, w = t >> 6, l = t & 63;
  const int lr = l & 15, hi = l >> 4, lk = hi * 8;
  const size_t base  = (size_t)b * 1024 * 512;
  const size_t vbase = (size_t)bh * 32 * 1024;

  const bf16x8 qf = *(const bf16x8*)&qkv[base + (size_t)(q0 + w * 16 + lr) * 512 + h * 32 + lk];

  f32x4 o0 = {0.f, 0.f, 0.f, 0.f}, o1 = {0.f, 0.f, 0.f, 0.f};
  f32x4 o_s = {0.f, 0.f, 0.f, 0.f};           // row-sum accumulator (lsum), q = hi*4+r
  f32x4 cneg = {0.f, 0.f, 0.f, 0.f};          // -m broadcast for QK C-operand (q = lr)
  const bf16x8 ones = {16256, 16256, 16256, 16256, 16256, 16256, 16256, 16256};  // bf16 1.0

  const int stok = t >> 2;         // K: token 0..63
  const int sd0  = (t & 3) * 8;    // K: 8 d elems
  // permuted K row: key k -> row ((k>>2)&1)*16 + ((k>>3)&3)*4 + (k&3) + (k&32)
  const int prow = ((stok >> 2) & 1) * 16 + ((stok >> 3) & 3) * 4 + (stok & 3) + (stok & 32);
  const int vsd  = t >> 3;         // V: d row 0..31
  const int vtk  = (t & 7) * 8;    // V: 8 tokens

  const unsigned short* pk = &qkv[base + (size_t)stok * 512 + 256 + h * 32 + sd0];
  const unsigned short* pv = &vt[vbase + (size_t)vsd * 1024 + vtk];
  bf16x8 nk = *(const bf16x8*)pk;
  bf16x8 nv = *(const bf16x8*)pv;

  for (int kc = 0; kc < 16; kc++) {
    __syncthreads();
    *(bf16x8*)&Ks[prow][sd0] = nk;
    *(bf16x8*)&Vs[vsd][vtk]  = nv;
    __syncthreads();

    if (kc < 15) {
      pk += 64 * 512;
      pv += 64;
      nk = *(const bf16x8*)pk;
      nv = *(const bf16x8*)pv;
    }

    // St = K_perm @ Q^T + (-m) : lane (lr,hi): s[blk][r] = score(q=lr, key=hi*8+(blk&1)*4+r+(blk>>1)*32) - m
    f32x4 s[4];
    __builtin_amdgcn_s_setprio(1);
#pragma unroll
    for (int blk = 0; blk < 4; blk++) {
      const bf16x8 kf = *(const bf16x8*)&Ks[blk * 16 + lr][lk];
      s[blk] = __builtin_amdgcn_mfma_f32_16x16x32_bf16(kf, qf, cneg, 0, 0, 0);
    }
    __builtin_amdgcn_s_setprio(0);

    // max of the 16 (max-subtracted) scores, v_max3-friendly tree
    const float pm = fmaxf(
        max3f(max3f(s[0][0], s[0][1], s[0][2]),
              max3f(s[0][3], s[1][0], s[1][1]),
              max3f(s[1][2], s[1][3], s[2][0])),
        max3f(max3f(s[2][1], s[2][2], s[2][3]),
              max3f(s[3][0], s[3][1], s[3][2]),
              s[3][3]));

    if (!__all(pm <= THR)) {  // defer-max slow path (cold)
      float mx = pm;
      mx = fmaxf(mx, __shfl_xor(mx, 16));
      mx = fmaxf(mx, __shfl_xor(mx, 32));
      const float dm = fmaxf(mx, 0.f);        // m_new - m_old for q = lr
#pragma unroll
      for (int r = 0; r < 4; r++) {
        const float a = EXPX(-__shfl(dm, hi * 4 + r));
        o0[r] *= a; o1[r] *= a; o_s[r] *= a;
      }
#pragma unroll
      for (int blk = 0; blk < 4; blk++)
#pragma unroll
        for (int r = 0; r < 4; r++) s[blk][r] -= dm;
#pragma unroll
      for (int r = 0; r < 4; r++) cneg[r] -= dm;
    }

    unsigned pu[8];
#pragma unroll
    for (int blk = 0; blk < 4; blk++) {
      const float p0 = EXPX(s[blk][0]);
      const float p1 = EXPX(s[blk][1]);
      const float p2 = EXPX(s[blk][2]);
      const float p3 = EXPX(s[blk][3]);
      pu[blk * 2]     = cvtpk(p0, p1);
      pu[blk * 2 + 1] = cvtpk(p2, p3);
    }

    union U { unsigned u[4]; bf16x8 v; };
    U a0, a1;
    a0.u[0] = pu[0]; a0.u[1] = pu[1]; a0.u[2] = pu[2]; a0.u[3] = pu[3];
    a1.u[0] = pu[4]; a1.u[1] = pu[5]; a1.u[2] = pu[6]; a1.u[3] = pu[7];

    // O += P @ V ; row-sum += P @ 1 (MFMA does the lsum reduction)
    __builtin_amdgcn_s_setprio(1);
#pragma unroll
    for (int ks = 0; ks < 2; ks++) {
      const bf16x8 pa  = (ks == 0) ? a0.v : a1.v;
      const bf16x8 v0f = *(const bf16x8*)&Vs[lr][ks * 32 + lk];
      const bf16x8 v1f = *(const bf16x8*)&Vs[16 + lr][ks * 32 + lk];
      o0  = __builtin_amdgcn_mfma_f32_16x16x32_bf16(pa, v0f, o0, 0, 0, 0);
      o1  = __builtin_amdgcn_mfma_f32_16x16x32_bf16(pa, v1f, o1, 0, 0, 0);
      o_s = __builtin_amdgcn_mfma_f32_16x16x32_bf16(pa, ones, o_s, 0, 0, 0);
    }
    __builtin_amdgcn_s_setprio(0);
  }

  // o_s[r] already holds the full denominator for q = hi*4+r (identical across lr)
#pragma unroll
  for (int r = 0; r < 4; r++) {
    const float inv = 1.f / o_s[r];
    const int row = q0 + w * 16 + hi * 4 + r;
    attn_out[(size_t)(b * 1024 + row) * 256 + h * 32 + lr]      = f2bf(o0[r] * inv);
    attn_out[(size_t)(b * 1024 + row) * 256 + h * 32 + 16 + lr] = f2bf(o1[r] * inv);
  }
}

// ---------------- LN2: y bf16 [tok][256] -> yln bf16 ----------------
__global__ __launch_bounds__(256) void k_ln2(const unsigned short* __restrict__ y,
                                             const float* __restrict__ g,
                                             const float* __restrict__ be,
                                             unsigned short* __restrict__ yln) {
  const int row = blockIdx.x * 4 + (threadIdx.x >> 6);
  const int l = threadIdx.x & 63;
  const unsigned short* yr = y + (size_t)row * 256;
  const ushort4 u = *(const ushort4*)(yr + l * 4);
  const float v0 = bf2f(u.x), v1 = bf2f(u.y), v2 = bf2f(u.z), v3 = bf2f(u.w);
  float s  = v0 + v1 + v2 + v3;
  float ss = v0 * v0 + v1 * v1 + v2 * v2 + v3 * v3;
#pragma unroll
  for (int msk = 1; msk < 64; msk <<= 1) {
    s  += __shfl_xor(s, msk);
    ss += __shfl_xor(ss, msk);
  }
  const float mean = s * (1.f / 256.f);
  const float var  = ss * (1.f / 256.f) - mean * mean;
  const float rs   = rsqrtf(var + 1e-5f);
  const float4 gv  = *(const float4*)(g + l * 4);
  const float4 bv  = *(const float4*)(be + l * 4);
  ushort4 o;
  o.x = f2bf((v0 - mean) * rs * gv.x + bv.x);
  o.y = f2bf((v1 - mean) * rs * gv.y + bv.y);
  o.z = f2bf((v2 - mean) * rs * gv.z + bv.z);
  o.w = f2bf((v3 - mean) * rs * gv.w + bv.w);
  *(ushort4*)&yln[(size_t)row * 256 + l * 4] = o;
}

// ---------------- launch ----------------
extern "C" void kernel_launch(void* const* d_in, const int* in_sizes, int n_in,
                              void* d_out, int out_size, void* d_ws, size_t ws_size,
                              hipStream_t stream) {
  const float* x      = (const float*)d_in[0];
  const float* w_qkv  = (const float*)d_in[1];
  const float* w_proj = (const float*)d_in[2];
  const float* b_proj = (const float*)d_in[3];
  const float* g1     = (const float*)d_in[4];
  const float* beta1  = (const float*)d_in[5];
  const float* g2     = (const float*)d_in[6];
  const float* beta2  = (const float*)d_in[7];
  const float* w1     = (const float*)d_in[8];
  const float* b1     = (const float*)d_in[9];
  const float* w2     = (const float*)d_in[10];
  const float* b2     = (const float*)d_in[11];
  float* out = (float*)d_out;
  char* ws = (char*)d_ws;

  constexpr size_t OFF_XT  = 0;                       //  8 MB bf16 [tok][256]
  constexpr size_t OFF_XLN = 16777216;                //  8 MB bf16
  constexpr size_t OFF_QKV = OFF_XLN + 8388608;       // 16 MB bf16 [tok][512] (Q,K only)
  constexpr size_t OFF_ATT = OFF_QKV + 16777216;      //  8 MB bf16
  constexpr size_t OFF_Y   = OFF_ATT + 8388608;       //  8 MB bf16 (aliases vT before GEMM<1>)
  constexpr size_t OFF_YLN = OFF_Y + 16777216;        //  8 MB bf16
  constexpr size_t OFF_W   = OFF_YLN + 8388608;       // weights bf16
  constexpr size_t OFF_H1  = OFF_XLN;                 // alias: 32 MB bf16 [tok][1024]
  constexpr size_t OFF_VT  = OFF_Y;                   // alias: 8 MB bf16 [bh][32][1024]

  unsigned short* xt    = (unsigned short*)(ws + OFF_XT);
  unsigned short* xln   = (unsigned short*)(ws + OFF_XLN);
  unsigned short* qkv   = (unsigned short*)(ws + OFF_QKV);
  unsigned short* attn  = (unsigned short*)(ws + OFF_ATT);
  unsigned short* y     = (unsigned short*)(ws + OFF_Y);
  unsigned short* yln   = (unsigned short*)(ws + OFF_YLN);
  unsigned short* h1    = (unsigned short*)(ws + OFF_H1);
  unsigned short* vtb   = (unsigned short*)(ws + OFF_VT);
  unsigned short* wqkvb = (unsigned short*)(ws + OFF_W);
  unsigned short* wprjb = (unsigned short*)(ws + OFF_W + 393216);
  unsigned short* w1b   = (unsigned short*)(ws + OFF_W + 393216 + 131072);
  unsigned short* w2b   = (unsigned short*)(ws + OFF_W + 393216 + 131072 + 524288);

  k_casts<<<768, 256, 0, stream>>>(w_qkv, w_proj, w1, w2, wqkvb, wprjb, w1b, w2b);

  k_ln1<<<dim3(32, 16), 256, 0, stream>>>(x, g1, beta1, xt, xln);

  // qkv = xln @ w_qkv^T : Q (pre-scaled),K -> qkv[tok][512]; V -> vT[bh][d][tok]
  k_gemm<0, 6, 128><<<768, 256, 0, stream>>>(xln, 256, wqkvb, 256, 256,
                                             nullptr, nullptr, 0, nullptr, qkv, 512, vtb);

  k_attn<<<2048, 256, 0, stream>>>(qkv, vtb, attn);

  // y = attn @ w_proj^T + b_proj + xt  (bf16)
  k_gemm<1, 2, 64><<<512, 256, 0, stream>>>(attn, 256, wprjb, 256, 256,
                                            b_proj, xt, 256, nullptr, y, 256, nullptr);

  k_ln2<<<4096, 256, 0, stream>>>(y, g2, beta2, yln);

  // h1 = relu(yln @ w1^T + b1)
  k_gemm<2, 8, 128><<<1024, 256, 0, stream>>>(yln, 256, w1b, 256, 256,
                                              b1, nullptr, 0, nullptr, h1, 1024, nullptr);

  // out = transpose(h1 @ w2^T + b2 + y)  (direct [b][c][s] write)
  k_gemm<3, 2, 64><<<512, 256, 0, stream>>>(h1, 1024, w2b, 1024, 1024,
                                            b2, y, 256, out, nullptr, 256, nullptr);
}